// Round 14
// baseline (290.164 us; speedup 1.0000x reference)
//
#include <hip/hip_runtime.h>
#include <math.h>

static constexpr int Tt = 32;
static constexpr int Nn = 1024;
static constexpr int KN = 16;   // K + self

// ---------------------------------------------------------------------------
// Cross-lane primitives: DPP for xor1/xor2 (pure VALU), ds_swizzle otherwise.
// ---------------------------------------------------------------------------
template <int M>
__device__ __forceinline__ float lane_xor(float v) {
    if constexpr (M == 1)
        return __int_as_float(__builtin_amdgcn_mov_dpp(__float_as_int(v), 0xB1, 0xF, 0xF, true));
    else if constexpr (M == 2)
        return __int_as_float(__builtin_amdgcn_mov_dpp(__float_as_int(v), 0x4E, 0xF, 0xF, true));
    else
        return __shfl_xor(v, M);
}
__device__ __forceinline__ float bcastlane(float v, int l) {
    return __int_as_float(__builtin_amdgcn_readlane(__float_as_int(v), l));
}
__device__ __forceinline__ constexpr int rev4(int k) {
    return ((k & 1) << 3) | ((k & 2) << 1) | ((k & 4) >> 1) | ((k & 8) >> 3);
}
template <int NV, int M>
__device__ __forceinline__ void fstage(float* p, int lane) {
#pragma unroll
    for (int k2 = 0; k2 < NV / 2; ++k2) {
        float a_ = p[k2], b_ = p[k2 + NV / 2];
        float t_ = (lane & M) ? a_ : b_;
        float r_ = lane_xor<M>(t_);
        p[k2] = ((lane & M) ? b_ : a_) + r_;
    }
}
__device__ __forceinline__ float fold16(float* p, int lane) {
    fstage<16, 1>(p, lane); fstage<8, 2>(p, lane);
    fstage<4, 4>(p, lane);  fstage<2, 8>(p, lane);
    return p[0];
}
__device__ __forceinline__ float rmax16(float x) {
    x = fmaxf(x, lane_xor<1>(x)); x = fmaxf(x, lane_xor<2>(x));
    x = fmaxf(x, lane_xor<4>(x)); x = fmaxf(x, lane_xor<8>(x));
    return x;
}
__device__ __forceinline__ float rsum16(float x) {
    x += lane_xor<1>(x); x += lane_xor<2>(x);
    x += lane_xor<4>(x); x += lane_xor<8>(x);
    return x;
}

// ---------------------------------------------------------------------------
// 1. Recover source indices (order-free), layout srcs[t][n][16].
// ---------------------------------------------------------------------------
__global__ __launch_bounds__(1024) void k_srcs(const int* __restrict__ edge,
                                               int* __restrict__ srcs)
{
    __shared__ int cnt[128];
    const int t    = blockIdx.x >> 3;
    const int tgt0 = (blockIdx.x & 7) << 7;
    const int x = threadIdx.x & 31;
    const int y = threadIdx.x >> 5;
    if (threadIdx.x < 128) cnt[threadIdx.x] = 0;
    __syncthreads();

    const int c0 = 4 * x;
    const int s0 = y * 32;
    const int* e = edge + (size_t)t * Nn * Nn + tgt0 + c0;

    for (int i0 = 0; i0 < 32; i0 += 8) {
        int4 v[8];
#pragma unroll
        for (int j = 0; j < 8; ++j)
            v[j] = *reinterpret_cast<const int4*>(e + (size_t)(s0 + i0 + j) * Nn);
#pragma unroll
        for (int j = 0; j < 8; ++j) {
            const int s = s0 + i0 + j;
            if (v[j].x) { int sl = atomicAdd(&cnt[c0],     1); if (sl < KN - 1) srcs[((size_t)t * Nn + tgt0 + c0)     * KN + sl] = s; }
            if (v[j].y) { int sl = atomicAdd(&cnt[c0 + 1], 1); if (sl < KN - 1) srcs[((size_t)t * Nn + tgt0 + c0 + 1) * KN + sl] = s; }
            if (v[j].z) { int sl = atomicAdd(&cnt[c0 + 2], 1); if (sl < KN - 1) srcs[((size_t)t * Nn + tgt0 + c0 + 2) * KN + sl] = s; }
            if (v[j].w) { int sl = atomicAdd(&cnt[c0 + 3], 1); if (sl < KN - 1) srcs[((size_t)t * Nn + tgt0 + c0 + 3) * KN + sl] = s; }
        }
    }
    if (threadIdx.x < 128)
        srcs[((size_t)t * Nn + tgt0 + threadIdx.x) * KN + (KN - 1)] = tgt0 + threadIdx.x;
}

// ---------------------------------------------------------------------------
// 2. Register-blocked dual linear, HEAD-INTERLEAVED float2 output (c, c+HC).
// ---------------------------------------------------------------------------
template <int FI, int FO>
__global__ __launch_bounds__(256) void k_lin2t(
    const float* __restrict__ X,
    const float* __restrict__ Wl, const float* __restrict__ bl,
    const float* __restrict__ Wr, const float* __restrict__ br,
    float* __restrict__ Yl, float* __restrict__ Yr, int rows)
{
    constexpr int HC = FO / 2;
    constexpr int RG = 256 / HC;
    constexpr int R  = 8;
    constexpr int BR = RG * R;
    constexpr int F4 = FI / 4;
    __shared__ float xs[BR][FI];

    const int tid  = threadIdx.x;
    const int c    = tid % HC;
    const int g    = tid / HC;
    const int row0 = blockIdx.x * BR;

#pragma unroll
    for (int idx = tid; idx < BR * F4; idx += 256) {
        int r = idx / F4, q = idx % F4;
        reinterpret_cast<float4*>(&xs[r][0])[q] =
            reinterpret_cast<const float4*>(X + (size_t)(row0 + r) * FI)[q];
    }
    __syncthreads();

    float al0[R], al1[R], ar0[R], ar1[R];
    const float bl0 = bl[c], bl1 = bl[c + HC], br0 = br[c], br1 = br[c + HC];
#pragma unroll
    for (int r = 0; r < R; ++r) { al0[r] = bl0; al1[r] = bl1; ar0[r] = br0; ar1[r] = br1; }

    const int rb = g * R;
#pragma unroll
    for (int i0 = 0; i0 < FI; i0 += 4) {
        float4 xv[R];
#pragma unroll
        for (int r = 0; r < R; ++r)
            xv[r] = *reinterpret_cast<const float4*>(&xs[rb + r][i0]);
#pragma unroll
        for (int j = 0; j < 4; ++j) {
            const float wl0 = Wl[(i0 + j) * FO + c];
            const float wl1 = Wl[(i0 + j) * FO + c + HC];
            const float wr0 = Wr[(i0 + j) * FO + c];
            const float wr1 = Wr[(i0 + j) * FO + c + HC];
#pragma unroll
            for (int r = 0; r < R; ++r) {
                const float xx = (&xv[r].x)[j];
                al0[r] = fmaf(xx, wl0, al0[r]);
                al1[r] = fmaf(xx, wl1, al1[r]);
                ar0[r] = fmaf(xx, wr0, ar0[r]);
                ar1[r] = fmaf(xx, wr1, ar1[r]);
            }
        }
    }
#pragma unroll
    for (int r = 0; r < R; ++r) {
        const size_t ro = (size_t)(row0 + rb + r) * FO;
        reinterpret_cast<float2*>(Yl + ro)[c] = make_float2(al0[r], al1[r]);
        reinterpret_cast<float2*>(Yr + ro)[c] = make_float2(ar0[r], ar1[r]);
    }
}

// ---------------------------------------------------------------------------
// 2m. Merged r1+f1 projection (one launch, pointer select).
// ---------------------------------------------------------------------------
__global__ __launch_bounds__(256) void k_lin2td(
    const float* __restrict__ E,
    const float* __restrict__ WlA, const float* __restrict__ blA,
    const float* __restrict__ WrA, const float* __restrict__ brA,
    float* __restrict__ YlA, float* __restrict__ YrA,
    const float* __restrict__ WlB, const float* __restrict__ blB,
    const float* __restrict__ WrB, const float* __restrict__ brB,
    float* __restrict__ YlB, float* __restrict__ YrB)
{
    constexpr int FI = 32, FO = 128, HC = 64, R = 8, BR = 32, F4 = FI / 4;
    __shared__ float xs[BR][FI];

    int bid = blockIdx.x;
    const bool second = bid >= 992;
    if (second) bid -= 992;

    const float* X  = second ? E   : (E + (size_t)Nn * FI);
    const float* Wl = second ? WlB : WlA;
    const float* bl = second ? blB : blA;
    const float* Wr = second ? WrB : WrA;
    const float* br = second ? brB : brA;
    float* Yl = second ? YlB : YlA;
    float* Yr = second ? YrB : YrA;

    const int tid  = threadIdx.x;
    const int c    = tid % HC;
    const int g    = tid / HC;
    const int row0 = bid * BR;

#pragma unroll
    for (int idx = tid; idx < BR * F4; idx += 256) {
        int r = idx / F4, q = idx % F4;
        reinterpret_cast<float4*>(&xs[r][0])[q] =
            reinterpret_cast<const float4*>(X + (size_t)(row0 + r) * FI)[q];
    }
    __syncthreads();

    float al0[R], al1[R], ar0[R], ar1[R];
    const float bl0 = bl[c], bl1 = bl[c + HC], br0 = br[c], br1 = br[c + HC];
#pragma unroll
    for (int r = 0; r < R; ++r) { al0[r] = bl0; al1[r] = bl1; ar0[r] = br0; ar1[r] = br1; }

    const int rb = g * R;
#pragma unroll
    for (int i0 = 0; i0 < FI; i0 += 4) {
        float4 xv[R];
#pragma unroll
        for (int r = 0; r < R; ++r)
            xv[r] = *reinterpret_cast<const float4*>(&xs[rb + r][i0]);
#pragma unroll
        for (int j = 0; j < 4; ++j) {
            const float wl0 = Wl[(i0 + j) * FO + c];
            const float wl1 = Wl[(i0 + j) * FO + c + HC];
            const float wr0 = Wr[(i0 + j) * FO + c];
            const float wr1 = Wr[(i0 + j) * FO + c + HC];
#pragma unroll
            for (int r = 0; r < R; ++r) {
                const float xx = (&xv[r].x)[j];
                al0[r] = fmaf(xx, wl0, al0[r]);
                al1[r] = fmaf(xx, wl1, al1[r]);
                ar0[r] = fmaf(xx, wr0, ar0[r]);
                ar1[r] = fmaf(xx, wr1, ar1[r]);
            }
        }
    }
#pragma unroll
    for (int r = 0; r < R; ++r) {
        const size_t ro = (size_t)(row0 + rb + r) * FO;
        reinterpret_cast<float2*>(Yl + ro)[c] = make_float2(al0[r], al1[r]);
        reinterpret_cast<float2*>(Yr + ro)[c] = make_float2(ar0[r], ar1[r]);
    }
}

// ---------------------------------------------------------------------------
// 2b. Single linear to 96 cols (GRU input gates): Y = X@W^T + b.
// ---------------------------------------------------------------------------
__global__ __launch_bounds__(192) void k_lin96(
    const float* __restrict__ X, const float* __restrict__ W,
    const float* __restrict__ b, float* __restrict__ Y)
{
    __shared__ float wT[32 * 97];
    __shared__ float xs[16][32];

    const int tid = threadIdx.y * 96 + threadIdx.x;
    const int row0 = blockIdx.x * 16;

    for (int idx = tid; idx < 3072; idx += 192) {
        int c = idx >> 5, i = idx & 31;
        wT[i * 97 + c] = W[idx];
    }
    for (int idx = tid; idx < 128; idx += 192)
        reinterpret_cast<float4*>(xs)[idx] =
            reinterpret_cast<const float4*>(X + (size_t)row0 * 32)[idx];
    __syncthreads();

    const int c  = threadIdx.x;
    const int rb = threadIdx.y * 8;
    float acc[8];
    const float bc = b[c];
#pragma unroll
    for (int r = 0; r < 8; ++r) acc[r] = bc;

#pragma unroll
    for (int i = 0; i < 32; ++i) {
        const float w = wT[i * 97 + c];
#pragma unroll
        for (int r = 0; r < 8; ++r)
            acc[r] = fmaf(xs[rb + r][i], w, acc[r]);
    }
#pragma unroll
    for (int r = 0; r < 8; ++r)
        Y[(size_t)(row0 + rb + r) * 96 + c] = acc[r];
}

// ---------------------------------------------------------------------------
// 2c. Serial GRU layer: register weights, shfl broadcast, next-t gi prefetch.
// ---------------------------------------------------------------------------
__global__ __launch_bounds__(64) void k_gru1(
    const float* __restrict__ gi, const float* __restrict__ Whh,
    const float* __restrict__ bhh, float* __restrict__ E)
{
    const int d    = threadIdx.x & 31;
    const int node = blockIdx.x * 2 + (threadIdx.x >> 5);

    float wr_[32], wz_[32], wn_[32];
#pragma unroll
    for (int q = 0; q < 8; ++q) {
        *reinterpret_cast<float4*>(&wr_[q * 4]) =
            reinterpret_cast<const float4*>(Whh + (size_t)d * 32)[q];
        *reinterpret_cast<float4*>(&wz_[q * 4]) =
            reinterpret_cast<const float4*>(Whh + (size_t)(32 + d) * 32)[q];
        *reinterpret_cast<float4*>(&wn_[q * 4]) =
            reinterpret_cast<const float4*>(Whh + (size_t)(64 + d) * 32)[q];
    }
    const float br_ = bhh[d], bz_ = bhh[32 + d], bn_ = bhh[64 + d];

    size_t base = (size_t)node * 96 + d;
    float gr = gi[base], gz = gi[base + 32], gn = gi[base + 64];

    float h = 0.0f;
    for (int t = 0; t < Tt; ++t) {
        float grn = 0.f, gzn = 0.f, gnn = 0.f;
        if (t < Tt - 1) {
            const size_t nb = ((size_t)(t + 1) * Nn + node) * 96 + d;
            grn = gi[nb]; gzn = gi[nb + 32]; gnn = gi[nb + 64];
        }
        float ar = br_, az = bz_, an = bn_;
#pragma unroll
        for (int i = 0; i < 32; ++i) {
            const float hv = __shfl(h, i, 32);
            ar = fmaf(wr_[i], hv, ar);
            az = fmaf(wz_[i], hv, az);
            an = fmaf(wn_[i], hv, an);
        }
        const float r = __builtin_amdgcn_rcpf(1.0f + expf(-(gr + ar)));
        const float z = __builtin_amdgcn_rcpf(1.0f + expf(-(gz + az)));
        const float nn2 = tanhf(gn + r * an);
        h = (1.0f - z) * nn2 + z * h;
        E[((size_t)t * Nn + node) * 32 + d] = h;
        gr = grn; gz = gzn; gn = gnn;
    }
}

// ---------------------------------------------------------------------------
// Shared GATv2 C=64 wave body: 32-bit voffset gather, DPP fold, readlane
// alpha broadcast. Returns ELU'd result.
// ---------------------------------------------------------------------------
__device__ __forceinline__ float gat64_body(
    const float* __restrict__ gl, const float* __restrict__ gr,
    const int* __restrict__ srcs, const float* __restrict__ att,
    const float* __restrict__ bias, int wave, int lane)
{
    const int t = wave >> 10;
    const int n = wave & (Nn - 1);

    const float2 grl = reinterpret_cast<const float2*>(gr + (size_t)wave * 128)[lane];
    const float a0 = att[lane], a1 = att[64 + lane];

    const int4* sp = reinterpret_cast<const int4*>(srcs + ((size_t)t * Nn + n) * KN);
    const int4 sA = sp[0], sB = sp[1], sC = sp[2], sD = sp[3];
    int s[KN] = {sA.x, sA.y, sA.z, sA.w, sB.x, sB.y, sB.z, sB.w,
                 sC.x, sC.y, sC.z, sC.w, sD.x, sD.y, sD.z, sD.w};

    const float2* glt = reinterpret_cast<const float2*>(gl) + ((size_t)t * Nn * 64);

    float2 g[KN];
    float p0[KN], p1[KN];
#pragma unroll
    for (int k = 0; k < KN; ++k) {
        g[k] = glt[(unsigned)((s[k] << 6) | lane)];
        float e0 = g[k].x + grl.x; e0 = fmaxf(e0, 0.2f * e0);
        float e1 = g[k].y + grl.y; e1 = fmaxf(e1, 0.2f * e1);
        p0[k] = e0 * a0; p1[k] = e1 * a1;
    }
    float lo0 = fold16(p0, lane);
    lo0 += lane_xor<16>(lo0); lo0 += __shfl_xor(lo0, 32);
    float lo1 = fold16(p1, lane);
    lo1 += lane_xor<16>(lo1); lo1 += __shfl_xor(lo1, 32);

    const float m0 = rmax16(lo0), m1 = rmax16(lo1);
    const float e0 = expf(lo0 - m0), e1 = expf(lo1 - m1);
    const float A0 = e0 * __builtin_amdgcn_rcpf(rsum16(e0));
    const float A1 = e1 * __builtin_amdgcn_rcpf(rsum16(e1));

    float acc0 = 0.0f, acc1 = 0.0f;
#pragma unroll
    for (int k = 0; k < KN; ++k) {
        acc0 = fmaf(bcastlane(A0, rev4(k)), g[k].x, acc0);
        acc1 = fmaf(bcastlane(A1, rev4(k)), g[k].y, acc1);
    }
    float res = 0.5f * (acc0 + acc1) + bias[lane];
    return res > 0.0f ? res : expm1f(res);
}

// ---------------------------------------------------------------------------
// 3. GATv2 C=64, plain output: out[row][64].
// ---------------------------------------------------------------------------
__global__ __launch_bounds__(256, 4) void k_gat64(
    const float* __restrict__ gl, const float* __restrict__ gr,
    const int* __restrict__ srcs, const float* __restrict__ att,
    const float* __restrict__ bias, float* __restrict__ out, int rows)
{
    const int lane = threadIdx.x & 63;
    const int w = threadIdx.x >> 6;
    const int gridB = rows >> 2;
    const int chunk = gridB >> 3;
    const int bid = blockIdx.x;
    const int lb = (bid & 7) * chunk + (bid >> 3);
    const int wave = lb * 4 + w;
    const float res = gat64_body(gl, gr, srcs, att, bias, wave, lane);
    out[(size_t)wave * 64 + lane] = res;
}

// ---------------------------------------------------------------------------
// 3b. GATv2 C=32: two targets per wave, fold within halves.
// ---------------------------------------------------------------------------
__global__ __launch_bounds__(256, 4) void k_gat32(
    const float* __restrict__ gl, const float* __restrict__ gr,
    const int* __restrict__ srcs, const float* __restrict__ att,
    const float* __restrict__ bias, float* __restrict__ out, int waves)
{
    const int lane = threadIdx.x & 63;
    const int w = threadIdx.x >> 6;
    const int gridB = waves >> 2;
    const int chunk = gridB >> 3;
    const int bid = blockIdx.x;
    const int lb = (bid & 7) * chunk + (bid >> 3);
    const int wv = lb * 4 + w;
    const int tgt = 2 * wv + (lane >> 5);
    const int t = tgt >> 10;
    const int n = tgt & (Nn - 1);
    const int c = lane & 31;

    const float2 grl = reinterpret_cast<const float2*>(gr + (size_t)tgt * 64)[c];
    const float a0 = att[c], a1 = att[32 + c];

    const int4* sp = reinterpret_cast<const int4*>(srcs + ((size_t)t * Nn + n) * KN);
    const int4 sA = sp[0], sB = sp[1], sC = sp[2], sD = sp[3];
    int s[KN] = {sA.x, sA.y, sA.z, sA.w, sB.x, sB.y, sB.z, sB.w,
                 sC.x, sC.y, sC.z, sC.w, sD.x, sD.y, sD.z, sD.w};

    const float2* glt = reinterpret_cast<const float2*>(gl) + ((size_t)t * Nn * 32);

    float2 g[KN];
    float p0[KN], p1[KN];
#pragma unroll
    for (int k = 0; k < KN; ++k) {
        g[k] = glt[(unsigned)((s[k] << 5) | c)];
        float e0 = g[k].x + grl.x; e0 = fmaxf(e0, 0.2f * e0);
        float e1 = g[k].y + grl.y; e1 = fmaxf(e1, 0.2f * e1);
        p0[k] = e0 * a0; p1[k] = e1 * a1;
    }
    float lo0 = fold16(p0, lane); lo0 += lane_xor<16>(lo0);
    float lo1 = fold16(p1, lane); lo1 += lane_xor<16>(lo1);

    const float m0 = rmax16(lo0), m1 = rmax16(lo1);
    const float e0 = expf(lo0 - m0), e1 = expf(lo1 - m1);
    const float A0 = e0 * __builtin_amdgcn_rcpf(rsum16(e0));
    const float A1 = e1 * __builtin_amdgcn_rcpf(rsum16(e1));

    const float A0o = __shfl_xor(A0, 32);
    const float A1o = __shfl_xor(A1, 32);
    const bool loHalf = (lane < 32);

    float acc0 = 0.0f, acc1 = 0.0f;
#pragma unroll
    for (int k = 0; k < KN; ++k) {
        const float b0a = bcastlane(A0, rev4(k)), b0b = bcastlane(A0o, rev4(k));
        const float b1a = bcastlane(A1, rev4(k)), b1b = bcastlane(A1o, rev4(k));
        acc0 = fmaf(loHalf ? b0a : b0b, g[k].x, acc0);
        acc1 = fmaf(loHalf ? b1a : b1b, g[k].y, acc1);
    }
    float res = 0.5f * (acc0 + acc1) + bias[c];
    res = res > 0.0f ? res : expm1f(res);
    out[(size_t)tgt * 32 + c] = res;
}

// ---------------------------------------------------------------------------
// 4. Dual register-blocked MLP head: out = tanh(in@W2+b2)@W3+b3.
//    32 rows/block; wave serves 8 rows -> weight loads amortized 8x
//    (16 VMEM/row vs 128 in the fused version). First 992 blocks = A
//    (recon), next 992 = B (fore). Shared W2/b2.
// ---------------------------------------------------------------------------
__global__ __launch_bounds__(256) void k_head2(
    const float* __restrict__ inA, const float* __restrict__ W3A,
    const float* __restrict__ b3A, float* __restrict__ outA,
    const float* __restrict__ inB, const float* __restrict__ W3B,
    const float* __restrict__ b3B, float* __restrict__ outB,
    const float* __restrict__ W2, const float* __restrict__ b2)
{
    __shared__ float xs[32][64];
    __shared__ float tmp[32][64];

    int bid = blockIdx.x;
    const bool second = bid >= 992;
    if (second) bid -= 992;

    const float* in  = second ? inB  : inA;
    const float* W3  = second ? W3B  : W3A;
    const float* b3  = second ? b3B  : b3A;
    float*       out = second ? outB : outA;

    const int c = threadIdx.x;      // 0..63 (output col / lane)
    const int g = threadIdx.y;      // 0..3  (row group)
    const int tid = g * 64 + c;
    const int row0 = bid * 32;

    // stage 32x64 input tile (float4 coalesced)
    for (int idx = tid; idx < 32 * 16; idx += 256) {
        int r = idx >> 4, q = idx & 15;
        reinterpret_cast<float4*>(&xs[r][0])[q] =
            reinterpret_cast<const float4*>(in + (size_t)(row0 + r) * 64)[q];
    }
    __syncthreads();

    const int rb = g * 8;
    float acc[8];
    const float bc = b2[c];
#pragma unroll
    for (int r = 0; r < 8; ++r) acc[r] = bc;
#pragma unroll
    for (int i = 0; i < 64; ++i) {
        const float w2 = W2[i * 64 + c];          // coalesced; shared by 8 rows
#pragma unroll
        for (int r = 0; r < 8; ++r)
            acc[r] = fmaf(xs[rb + r][i], w2, acc[r]);   // LDS broadcast
    }
#pragma unroll
    for (int r = 0; r < 8; ++r) tmp[rb + r][c] = tanhf(acc[r]);
    // tmp rows rb..rb+7 are written and read by the SAME wave (lockstep) — no barrier.

    const int cc = c < 50 ? c : 0;
    float a[8];
    const float b3c = b3[cc];
#pragma unroll
    for (int r = 0; r < 8; ++r) a[r] = b3c;
#pragma unroll
    for (int j = 0; j < 64; ++j) {
        const float w3 = W3[j * 50 + cc];
#pragma unroll
        for (int r = 0; r < 8; ++r)
            a[r] = fmaf(tmp[rb + r][j], w3, a[r]);      // LDS broadcast
    }
    if (c < 50) {
#pragma unroll
        for (int r = 0; r < 8; ++r)
            out[(size_t)(row0 + rb + r) * 50 + c] = a[r];
    }
}

// ---------------------------------------------------------------------------
extern "C" void kernel_launch(void* const* d_in, const int* in_sizes, int n_in,
                              void* d_out, int out_size, void* d_ws, size_t ws_size,
                              hipStream_t stream)
{
    const float* x    = (const float*)d_in[0];
    const int*   edge = (const int*)d_in[1];

    const float *g1_Wl = (const float*)d_in[2],  *g1_bl = (const float*)d_in[3];
    const float *g1_Wr = (const float*)d_in[4],  *g1_br = (const float*)d_in[5];
    const float *g1_att= (const float*)d_in[6],  *g1_b  = (const float*)d_in[7];
    const float *g2_Wl = (const float*)d_in[8],  *g2_bl = (const float*)d_in[9];
    const float *g2_Wr = (const float*)d_in[10], *g2_br = (const float*)d_in[11];
    const float *g2_att= (const float*)d_in[12], *g2_b  = (const float*)d_in[13];
    const float *r1_Wl = (const float*)d_in[14], *r1_bl = (const float*)d_in[15];
    const float *r1_Wr = (const float*)d_in[16], *r1_br = (const float*)d_in[17];
    const float *r1_att= (const float*)d_in[18], *r1_b  = (const float*)d_in[19];
    const float *f1_Wl = (const float*)d_in[20], *f1_bl = (const float*)d_in[21];
    const float *f1_Wr = (const float*)d_in[22], *f1_br = (const float*)d_in[23];
    const float *f1_att= (const float*)d_in[24], *f1_b  = (const float*)d_in[25];
    const float *gru0_Wih = (const float*)d_in[26], *gru0_Whh = (const float*)d_in[27];
    const float *gru0_bih = (const float*)d_in[28], *gru0_bhh = (const float*)d_in[29];
    const float *gru1_Wih = (const float*)d_in[30], *gru1_Whh = (const float*)d_in[31];
    const float *gru1_bih = (const float*)d_in[32], *gru1_bhh = (const float*)d_in[33];
    const float *rec2_W = (const float*)d_in[34], *rec2_b = (const float*)d_in[35];
    const float *rec3_W = (const float*)d_in[36], *rec3_b = (const float*)d_in[37];
    const float *fore3_W= (const float*)d_in[38], *fore3_b= (const float*)d_in[39];

    // workspace layout
    char* ws = (char*)d_ws;
    int*   srcs = (int*)ws;                              // [32][1024][16] (2 MB)
    float* buf1 = (float*)(ws + (4u << 20));             // [32768,128] 16.78 MB
    float* buf2 = buf1 + (size_t)32768 * 128;
    float* buf3 = buf2 + (size_t)32768 * 128;
    float* buf4 = buf3 + (size_t)32768 * 128;
    float* buf5 = buf4 + (size_t)32768 * 128;            // [32768,64]
    float* buf6 = buf5 + (size_t)32768 * 64;             // [32768,32]

    float* recon = (float*)d_out;                        // [31,1024,50]
    float* fore  = recon + (size_t)31 * 1024 * 50;       // [31,1024,50]
    float* E     = fore  + (size_t)31 * 1024 * 50;       // [32,1024,32]

    // 1. adjacency -> source lists
    k_srcs<<<Tt * 8, 1024, 0, stream>>>(edge, srcs);

    // 2. GAT g1 (64 -> 64)
    k_lin2t<64, 128><<<1024, 256, 0, stream>>>(x, g1_Wl, g1_bl, g1_Wr, g1_br, buf1, buf2, 32768);
    k_gat64<<<8192, 256, 0, stream>>>(buf1, buf2, srcs, g1_att, g1_b, buf5, 32768);

    // 3. GAT g2 (64 -> 32)
    k_lin2t<64, 64><<<512, 256, 0, stream>>>(buf5, g2_Wl, g2_bl, g2_Wr, g2_br, buf1, buf2, 32768);
    k_gat32<<<4096, 256, 0, stream>>>(buf1, buf2, srcs, g2_att, g2_b, buf6, 16384);

    // 4. GRU stack
    k_lin96<<<2048, dim3(96, 2), 0, stream>>>(buf6, gru0_Wih, gru0_bih, buf1);   // GI0
    k_gru1<<<512, 64, 0, stream>>>(buf1, gru0_Whh, gru0_bhh, buf5);              // E0
    k_lin96<<<2048, dim3(96, 2), 0, stream>>>(buf5, gru1_Wih, gru1_bih, buf2);   // GI1
    k_gru1<<<512, 64, 0, stream>>>(buf2, gru1_Whh, gru1_bhh, E);                 // E

    // 5. r1+f1 projections in one launch
    k_lin2td<<<1984, 256, 0, stream>>>(E,
        r1_Wl, r1_bl, r1_Wr, r1_br, buf1, buf2,
        f1_Wl, f1_bl, f1_Wr, f1_br, buf3, buf4);

    // 6. GAT bodies (stride-64 res), then register-blocked dual head
    k_gat64<<<7936, 256, 0, stream>>>(buf1, buf2, srcs + (size_t)KN * Nn, r1_att, r1_b, buf5, 31744);
    k_gat64<<<7936, 256, 0, stream>>>(buf3, buf4, srcs, f1_att, f1_b, buf1, 31744);  // buf1 free after body-A
    k_head2<<<1984, dim3(64, 4), 0, stream>>>(
        buf5, rec3_W, rec3_b, recon,
        buf1, fore3_W, fore3_b, fore,
        rec2_W, rec2_b);

    (void)in_sizes; (void)n_in; (void)out_size; (void)ws_size;
}

// Round 15
// 283.578 us; speedup vs baseline: 1.0232x; 1.0232x over previous
//
#include <hip/hip_runtime.h>
#include <math.h>

static constexpr int Tt = 32;
static constexpr int Nn = 1024;
static constexpr int KN = 16;   // K + self

// ---------------------------------------------------------------------------
// Cross-lane primitives: DPP for xor1/xor2 (pure VALU), ds_swizzle otherwise.
// ---------------------------------------------------------------------------
template <int M>
__device__ __forceinline__ float lane_xor(float v) {
    if constexpr (M == 1)
        return __int_as_float(__builtin_amdgcn_mov_dpp(__float_as_int(v), 0xB1, 0xF, 0xF, true));
    else if constexpr (M == 2)
        return __int_as_float(__builtin_amdgcn_mov_dpp(__float_as_int(v), 0x4E, 0xF, 0xF, true));
    else
        return __shfl_xor(v, M);
}
__device__ __forceinline__ float bcastlane(float v, int l) {
    return __int_as_float(__builtin_amdgcn_readlane(__float_as_int(v), l));
}
__device__ __forceinline__ constexpr int rev4(int k) {
    return ((k & 1) << 3) | ((k & 2) << 1) | ((k & 4) >> 1) | ((k & 8) >> 3);
}
template <int NV, int M>
__device__ __forceinline__ void fstage(float* p, int lane) {
#pragma unroll
    for (int k2 = 0; k2 < NV / 2; ++k2) {
        float a_ = p[k2], b_ = p[k2 + NV / 2];
        float t_ = (lane & M) ? a_ : b_;
        float r_ = lane_xor<M>(t_);
        p[k2] = ((lane & M) ? b_ : a_) + r_;
    }
}
__device__ __forceinline__ float fold16(float* p, int lane) {
    fstage<16, 1>(p, lane); fstage<8, 2>(p, lane);
    fstage<4, 4>(p, lane);  fstage<2, 8>(p, lane);
    return p[0];
}
__device__ __forceinline__ float rmax16(float x) {
    x = fmaxf(x, lane_xor<1>(x)); x = fmaxf(x, lane_xor<2>(x));
    x = fmaxf(x, lane_xor<4>(x)); x = fmaxf(x, lane_xor<8>(x));
    return x;
}
__device__ __forceinline__ float rsum16(float x) {
    x += lane_xor<1>(x); x += lane_xor<2>(x);
    x += lane_xor<4>(x); x += lane_xor<8>(x);
    return x;
}

// ---------------------------------------------------------------------------
// 1. Recover source indices (order-free), layout srcs[t][n][16].
// ---------------------------------------------------------------------------
__global__ __launch_bounds__(1024) void k_srcs(const int* __restrict__ edge,
                                               int* __restrict__ srcs)
{
    __shared__ int cnt[128];
    const int t    = blockIdx.x >> 3;
    const int tgt0 = (blockIdx.x & 7) << 7;
    const int x = threadIdx.x & 31;
    const int y = threadIdx.x >> 5;
    if (threadIdx.x < 128) cnt[threadIdx.x] = 0;
    __syncthreads();

    const int c0 = 4 * x;
    const int s0 = y * 32;
    const int* e = edge + (size_t)t * Nn * Nn + tgt0 + c0;

    for (int i0 = 0; i0 < 32; i0 += 8) {
        int4 v[8];
#pragma unroll
        for (int j = 0; j < 8; ++j)
            v[j] = *reinterpret_cast<const int4*>(e + (size_t)(s0 + i0 + j) * Nn);
#pragma unroll
        for (int j = 0; j < 8; ++j) {
            const int s = s0 + i0 + j;
            if (v[j].x) { int sl = atomicAdd(&cnt[c0],     1); if (sl < KN - 1) srcs[((size_t)t * Nn + tgt0 + c0)     * KN + sl] = s; }
            if (v[j].y) { int sl = atomicAdd(&cnt[c0 + 1], 1); if (sl < KN - 1) srcs[((size_t)t * Nn + tgt0 + c0 + 1) * KN + sl] = s; }
            if (v[j].z) { int sl = atomicAdd(&cnt[c0 + 2], 1); if (sl < KN - 1) srcs[((size_t)t * Nn + tgt0 + c0 + 2) * KN + sl] = s; }
            if (v[j].w) { int sl = atomicAdd(&cnt[c0 + 3], 1); if (sl < KN - 1) srcs[((size_t)t * Nn + tgt0 + c0 + 3) * KN + sl] = s; }
        }
    }
    if (threadIdx.x < 128)
        srcs[((size_t)t * Nn + tgt0 + threadIdx.x) * KN + (KN - 1)] = tgt0 + threadIdx.x;
}

// ---------------------------------------------------------------------------
// 2. Register-blocked dual linear, HEAD-INTERLEAVED float2 output (c, c+HC).
// ---------------------------------------------------------------------------
template <int FI, int FO>
__global__ __launch_bounds__(256) void k_lin2t(
    const float* __restrict__ X,
    const float* __restrict__ Wl, const float* __restrict__ bl,
    const float* __restrict__ Wr, const float* __restrict__ br,
    float* __restrict__ Yl, float* __restrict__ Yr, int rows)
{
    constexpr int HC = FO / 2;
    constexpr int RG = 256 / HC;
    constexpr int R  = 8;
    constexpr int BR = RG * R;
    constexpr int F4 = FI / 4;
    __shared__ float xs[BR][FI];

    const int tid  = threadIdx.x;
    const int c    = tid % HC;
    const int g    = tid / HC;
    const int row0 = blockIdx.x * BR;

#pragma unroll
    for (int idx = tid; idx < BR * F4; idx += 256) {
        int r = idx / F4, q = idx % F4;
        reinterpret_cast<float4*>(&xs[r][0])[q] =
            reinterpret_cast<const float4*>(X + (size_t)(row0 + r) * FI)[q];
    }
    __syncthreads();

    float al0[R], al1[R], ar0[R], ar1[R];
    const float bl0 = bl[c], bl1 = bl[c + HC], br0 = br[c], br1 = br[c + HC];
#pragma unroll
    for (int r = 0; r < R; ++r) { al0[r] = bl0; al1[r] = bl1; ar0[r] = br0; ar1[r] = br1; }

    const int rb = g * R;
#pragma unroll
    for (int i0 = 0; i0 < FI; i0 += 4) {
        float4 xv[R];
#pragma unroll
        for (int r = 0; r < R; ++r)
            xv[r] = *reinterpret_cast<const float4*>(&xs[rb + r][i0]);
#pragma unroll
        for (int j = 0; j < 4; ++j) {
            const float wl0 = Wl[(i0 + j) * FO + c];
            const float wl1 = Wl[(i0 + j) * FO + c + HC];
            const float wr0 = Wr[(i0 + j) * FO + c];
            const float wr1 = Wr[(i0 + j) * FO + c + HC];
#pragma unroll
            for (int r = 0; r < R; ++r) {
                const float xx = (&xv[r].x)[j];
                al0[r] = fmaf(xx, wl0, al0[r]);
                al1[r] = fmaf(xx, wl1, al1[r]);
                ar0[r] = fmaf(xx, wr0, ar0[r]);
                ar1[r] = fmaf(xx, wr1, ar1[r]);
            }
        }
    }
#pragma unroll
    for (int r = 0; r < R; ++r) {
        const size_t ro = (size_t)(row0 + rb + r) * FO;
        reinterpret_cast<float2*>(Yl + ro)[c] = make_float2(al0[r], al1[r]);
        reinterpret_cast<float2*>(Yr + ro)[c] = make_float2(ar0[r], ar1[r]);
    }
}

// ---------------------------------------------------------------------------
// 2m. Merged r1+f1 projection (one launch, pointer select).
// ---------------------------------------------------------------------------
__global__ __launch_bounds__(256) void k_lin2td(
    const float* __restrict__ E,
    const float* __restrict__ WlA, const float* __restrict__ blA,
    const float* __restrict__ WrA, const float* __restrict__ brA,
    float* __restrict__ YlA, float* __restrict__ YrA,
    const float* __restrict__ WlB, const float* __restrict__ blB,
    const float* __restrict__ WrB, const float* __restrict__ brB,
    float* __restrict__ YlB, float* __restrict__ YrB)
{
    constexpr int FI = 32, FO = 128, HC = 64, R = 8, BR = 32, F4 = FI / 4;
    __shared__ float xs[BR][FI];

    int bid = blockIdx.x;
    const bool second = bid >= 992;
    if (second) bid -= 992;

    const float* X  = second ? E   : (E + (size_t)Nn * FI);
    const float* Wl = second ? WlB : WlA;
    const float* bl = second ? blB : blA;
    const float* Wr = second ? WrB : WrA;
    const float* br = second ? brB : brA;
    float* Yl = second ? YlB : YlA;
    float* Yr = second ? YrB : YrA;

    const int tid  = threadIdx.x;
    const int c    = tid % HC;
    const int g    = tid / HC;
    const int row0 = bid * BR;

#pragma unroll
    for (int idx = tid; idx < BR * F4; idx += 256) {
        int r = idx / F4, q = idx % F4;
        reinterpret_cast<float4*>(&xs[r][0])[q] =
            reinterpret_cast<const float4*>(X + (size_t)(row0 + r) * FI)[q];
    }
    __syncthreads();

    float al0[R], al1[R], ar0[R], ar1[R];
    const float bl0 = bl[c], bl1 = bl[c + HC], br0 = br[c], br1 = br[c + HC];
#pragma unroll
    for (int r = 0; r < R; ++r) { al0[r] = bl0; al1[r] = bl1; ar0[r] = br0; ar1[r] = br1; }

    const int rb = g * R;
#pragma unroll
    for (int i0 = 0; i0 < FI; i0 += 4) {
        float4 xv[R];
#pragma unroll
        for (int r = 0; r < R; ++r)
            xv[r] = *reinterpret_cast<const float4*>(&xs[rb + r][i0]);
#pragma unroll
        for (int j = 0; j < 4; ++j) {
            const float wl0 = Wl[(i0 + j) * FO + c];
            const float wl1 = Wl[(i0 + j) * FO + c + HC];
            const float wr0 = Wr[(i0 + j) * FO + c];
            const float wr1 = Wr[(i0 + j) * FO + c + HC];
#pragma unroll
            for (int r = 0; r < R; ++r) {
                const float xx = (&xv[r].x)[j];
                al0[r] = fmaf(xx, wl0, al0[r]);
                al1[r] = fmaf(xx, wl1, al1[r]);
                ar0[r] = fmaf(xx, wr0, ar0[r]);
                ar1[r] = fmaf(xx, wr1, ar1[r]);
            }
        }
    }
#pragma unroll
    for (int r = 0; r < R; ++r) {
        const size_t ro = (size_t)(row0 + rb + r) * FO;
        reinterpret_cast<float2*>(Yl + ro)[c] = make_float2(al0[r], al1[r]);
        reinterpret_cast<float2*>(Yr + ro)[c] = make_float2(ar0[r], ar1[r]);
    }
}

// ---------------------------------------------------------------------------
// 2b. Single linear to 96 cols (GRU input gates): Y = X@W^T + b.
// ---------------------------------------------------------------------------
__global__ __launch_bounds__(192) void k_lin96(
    const float* __restrict__ X, const float* __restrict__ W,
    const float* __restrict__ b, float* __restrict__ Y)
{
    __shared__ float wT[32 * 97];
    __shared__ float xs[16][32];

    const int tid = threadIdx.y * 96 + threadIdx.x;
    const int row0 = blockIdx.x * 16;

    for (int idx = tid; idx < 3072; idx += 192) {
        int c = idx >> 5, i = idx & 31;
        wT[i * 97 + c] = W[idx];
    }
    for (int idx = tid; idx < 128; idx += 192)
        reinterpret_cast<float4*>(xs)[idx] =
            reinterpret_cast<const float4*>(X + (size_t)row0 * 32)[idx];
    __syncthreads();

    const int c  = threadIdx.x;
    const int rb = threadIdx.y * 8;
    float acc[8];
    const float bc = b[c];
#pragma unroll
    for (int r = 0; r < 8; ++r) acc[r] = bc;

#pragma unroll
    for (int i = 0; i < 32; ++i) {
        const float w = wT[i * 97 + c];
#pragma unroll
        for (int r = 0; r < 8; ++r)
            acc[r] = fmaf(xs[rb + r][i], w, acc[r]);
    }
#pragma unroll
    for (int r = 0; r < 8; ++r)
        Y[(size_t)(row0 + rb + r) * 96 + c] = acc[r];
}

// ---------------------------------------------------------------------------
// 2c. Serial GRU layer: register weights, shfl broadcast, next-t gi prefetch.
// ---------------------------------------------------------------------------
__global__ __launch_bounds__(64) void k_gru1(
    const float* __restrict__ gi, const float* __restrict__ Whh,
    const float* __restrict__ bhh, float* __restrict__ E)
{
    const int d    = threadIdx.x & 31;
    const int node = blockIdx.x * 2 + (threadIdx.x >> 5);

    float wr_[32], wz_[32], wn_[32];
#pragma unroll
    for (int q = 0; q < 8; ++q) {
        *reinterpret_cast<float4*>(&wr_[q * 4]) =
            reinterpret_cast<const float4*>(Whh + (size_t)d * 32)[q];
        *reinterpret_cast<float4*>(&wz_[q * 4]) =
            reinterpret_cast<const float4*>(Whh + (size_t)(32 + d) * 32)[q];
        *reinterpret_cast<float4*>(&wn_[q * 4]) =
            reinterpret_cast<const float4*>(Whh + (size_t)(64 + d) * 32)[q];
    }
    const float br_ = bhh[d], bz_ = bhh[32 + d], bn_ = bhh[64 + d];

    size_t base = (size_t)node * 96 + d;
    float gr = gi[base], gz = gi[base + 32], gn = gi[base + 64];

    float h = 0.0f;
    for (int t = 0; t < Tt; ++t) {
        float grn = 0.f, gzn = 0.f, gnn = 0.f;
        if (t < Tt - 1) {
            const size_t nb = ((size_t)(t + 1) * Nn + node) * 96 + d;
            grn = gi[nb]; gzn = gi[nb + 32]; gnn = gi[nb + 64];
        }
        float ar = br_, az = bz_, an = bn_;
#pragma unroll
        for (int i = 0; i < 32; ++i) {
            const float hv = __shfl(h, i, 32);
            ar = fmaf(wr_[i], hv, ar);
            az = fmaf(wz_[i], hv, az);
            an = fmaf(wn_[i], hv, an);
        }
        const float r = __builtin_amdgcn_rcpf(1.0f + expf(-(gr + ar)));
        const float z = __builtin_amdgcn_rcpf(1.0f + expf(-(gz + az)));
        const float nn2 = tanhf(gn + r * an);
        h = (1.0f - z) * nn2 + z * h;
        E[((size_t)t * Nn + node) * 32 + d] = h;
        gr = grn; gz = gzn; gn = gnn;
    }
}

// ---------------------------------------------------------------------------
// Shared GATv2 C=64 PAIR body: TWO targets per wave (one per 32-lane half,
// like k_gat32). Lane holds channel slots c and 32+c (each a float2 =
// (head0 ch, head1 ch)). One fold/softmax pass serves both targets.
// Writes res for channels c and 32+c of its half's target.
// ---------------------------------------------------------------------------
__device__ __forceinline__ void gat64_pair_body(
    const float* __restrict__ gl, const float* __restrict__ gr,
    const int* __restrict__ srcs, const float* __restrict__ att,
    const float* __restrict__ bias, int wv, int lane,
    float* __restrict__ out)
{
    const int tgt = 2 * wv + (lane >> 5);    // both targets share t (2wv even)
    const int t = tgt >> 10;
    const int n = tgt & (Nn - 1);
    const int c = lane & 31;

    const float2* grrow = reinterpret_cast<const float2*>(gr) + (size_t)tgt * 64;
    const float2 grl0 = grrow[c];            // (h0 ch c,    h1 ch c)
    const float2 grl1 = grrow[32 + c];       // (h0 ch 32+c, h1 ch 32+c)
    const float a00 = att[c],      a01 = att[32 + c];       // head0
    const float a10 = att[64 + c], a11 = att[96 + c];       // head1

    const int4* sp = reinterpret_cast<const int4*>(srcs + ((size_t)t * Nn + n) * KN);
    const int4 sA = sp[0], sB = sp[1], sC = sp[2], sD = sp[3];
    int s[KN] = {sA.x, sA.y, sA.z, sA.w, sB.x, sB.y, sB.z, sB.w,
                 sC.x, sC.y, sC.z, sC.w, sD.x, sD.y, sD.z, sD.w};

    const float2* glt = reinterpret_cast<const float2*>(gl) + ((size_t)t * Nn * 64);

    float2 g0[KN], g1[KN];
    float p0[KN], p1[KN];
#pragma unroll
    for (int k = 0; k < KN; ++k) {
        const unsigned ro = (unsigned)(s[k] << 6);
        g0[k] = glt[ro | c];
        g1[k] = glt[ro | (32 + c)];
        float e00 = g0[k].x + grl0.x; e00 = fmaxf(e00, 0.2f * e00);
        float e01 = g1[k].x + grl1.x; e01 = fmaxf(e01, 0.2f * e01);
        float e10 = g0[k].y + grl0.y; e10 = fmaxf(e10, 0.2f * e10);
        float e11 = g1[k].y + grl1.y; e11 = fmaxf(e11, 0.2f * e11);
        p0[k] = fmaf(e01, a01, e00 * a00);   // head0 partial (2 ch)
        p1[k] = fmaf(e11, a11, e10 * a10);   // head1 partial (2 ch)
    }
    // fold within 32-lane halves: logit[k] at (lane&15)==rev4(k); finish ch sum
    float lo0 = fold16(p0, lane); lo0 += lane_xor<16>(lo0);
    float lo1 = fold16(p1, lane); lo1 += lane_xor<16>(lo1);

    const float m0 = rmax16(lo0), m1 = rmax16(lo1);
    const float e0 = expf(lo0 - m0), e1 = expf(lo1 - m1);
    const float A0 = e0 * __builtin_amdgcn_rcpf(rsum16(e0));
    const float A1 = e1 * __builtin_amdgcn_rcpf(rsum16(e1));

    const float A0o = __shfl_xor(A0, 32);
    const float A1o = __shfl_xor(A1, 32);
    const bool loHalf = (lane < 32);

    float acc00 = 0.0f, acc01 = 0.0f, acc10 = 0.0f, acc11 = 0.0f;
#pragma unroll
    for (int k = 0; k < KN; ++k) {
        const float b0a = bcastlane(A0, rev4(k)), b0b = bcastlane(A0o, rev4(k));
        const float b1a = bcastlane(A1, rev4(k)), b1b = bcastlane(A1o, rev4(k));
        const float b0 = loHalf ? b0a : b0b;
        const float b1 = loHalf ? b1a : b1b;
        acc00 = fmaf(b0, g0[k].x, acc00);    // head0 ch c
        acc01 = fmaf(b0, g1[k].x, acc01);    // head0 ch 32+c
        acc10 = fmaf(b1, g0[k].y, acc10);    // head1 ch c
        acc11 = fmaf(b1, g1[k].y, acc11);    // head1 ch 32+c
    }
    float r0 = 0.5f * (acc00 + acc10) + bias[c];
    float r1 = 0.5f * (acc01 + acc11) + bias[32 + c];
    r0 = r0 > 0.0f ? r0 : expm1f(r0);
    r1 = r1 > 0.0f ? r1 : expm1f(r1);
    out[(size_t)tgt * 64 + c]      = r0;
    out[(size_t)tgt * 64 + 32 + c] = r1;
}

// ---------------------------------------------------------------------------
// 3. GATv2 C=64 pair kernel (g1): pairs = rows/2, 4 pair-waves per block.
// ---------------------------------------------------------------------------
__global__ __launch_bounds__(256, 3) void k_gat64p(
    const float* __restrict__ gl, const float* __restrict__ gr,
    const int* __restrict__ srcs, const float* __restrict__ att,
    const float* __restrict__ bias, float* __restrict__ out, int pairs)
{
    const int lane = threadIdx.x & 63;
    const int w = threadIdx.x >> 6;
    const int gridB = pairs >> 2;
    const int chunk = gridB >> 3;
    const int bid = blockIdx.x;
    const int lb = (bid & 7) * chunk + (bid >> 3);
    const int wv = lb * 4 + w;
    gat64_pair_body(gl, gr, srcs, att, bias, wv, lane, out);
}

// ---------------------------------------------------------------------------
// 3d. Dual-path GATv2 C=64 pair kernel (r1 + f1 tails in one launch).
//     First 3968 blocks = A (recon path), next 3968 = B (forecast path).
// ---------------------------------------------------------------------------
__global__ __launch_bounds__(256, 3) void k_gat64p2(
    const float* __restrict__ glA, const float* __restrict__ grA,
    const int* __restrict__ srcsA, const float* __restrict__ attA,
    const float* __restrict__ biasA, float* __restrict__ outA,
    const float* __restrict__ glB, const float* __restrict__ grB,
    const int* __restrict__ srcsB, const float* __restrict__ attB,
    const float* __restrict__ biasB, float* __restrict__ outB)
{
    constexpr int pairs = (Tt - 1) * Nn / 2;   // 15872
    constexpr int gridH = pairs >> 2;           // 3968
    constexpr int chunk = gridH >> 3;           // 496

    int bid = blockIdx.x;
    const bool second = bid >= gridH;
    if (second) bid -= gridH;

    const float* gl   = second ? glB   : glA;
    const float* gr   = second ? grB   : grA;
    const int*   srcs = second ? srcsB : srcsA;
    const float* att  = second ? attB  : attA;
    const float* bias = second ? biasB : biasA;
    float*       out  = second ? outB  : outA;

    const int lane = threadIdx.x & 63;
    const int w = threadIdx.x >> 6;
    const int lb = (bid & 7) * chunk + (bid >> 3);
    const int wv = lb * 4 + w;
    gat64_pair_body(gl, gr, srcs, att, bias, wv, lane, out);
}

// ---------------------------------------------------------------------------
// 3b. GATv2 C=32: two targets per wave, fold within halves.
// ---------------------------------------------------------------------------
__global__ __launch_bounds__(256, 4) void k_gat32(
    const float* __restrict__ gl, const float* __restrict__ gr,
    const int* __restrict__ srcs, const float* __restrict__ att,
    const float* __restrict__ bias, float* __restrict__ out, int waves)
{
    const int lane = threadIdx.x & 63;
    const int w = threadIdx.x >> 6;
    const int gridB = waves >> 2;
    const int chunk = gridB >> 3;
    const int bid = blockIdx.x;
    const int lb = (bid & 7) * chunk + (bid >> 3);
    const int wv = lb * 4 + w;
    const int tgt = 2 * wv + (lane >> 5);
    const int t = tgt >> 10;
    const int n = tgt & (Nn - 1);
    const int c = lane & 31;

    const float2 grl = reinterpret_cast<const float2*>(gr + (size_t)tgt * 64)[c];
    const float a0 = att[c], a1 = att[32 + c];

    const int4* sp = reinterpret_cast<const int4*>(srcs + ((size_t)t * Nn + n) * KN);
    const int4 sA = sp[0], sB = sp[1], sC = sp[2], sD = sp[3];
    int s[KN] = {sA.x, sA.y, sA.z, sA.w, sB.x, sB.y, sB.z, sB.w,
                 sC.x, sC.y, sC.z, sC.w, sD.x, sD.y, sD.z, sD.w};

    const float2* glt = reinterpret_cast<const float2*>(gl) + ((size_t)t * Nn * 32);

    float2 g[KN];
    float p0[KN], p1[KN];
#pragma unroll
    for (int k = 0; k < KN; ++k) {
        g[k] = glt[(unsigned)((s[k] << 5) | c)];
        float e0 = g[k].x + grl.x; e0 = fmaxf(e0, 0.2f * e0);
        float e1 = g[k].y + grl.y; e1 = fmaxf(e1, 0.2f * e1);
        p0[k] = e0 * a0; p1[k] = e1 * a1;
    }
    float lo0 = fold16(p0, lane); lo0 += lane_xor<16>(lo0);
    float lo1 = fold16(p1, lane); lo1 += lane_xor<16>(lo1);

    const float m0 = rmax16(lo0), m1 = rmax16(lo1);
    const float e0 = expf(lo0 - m0), e1 = expf(lo1 - m1);
    const float A0 = e0 * __builtin_amdgcn_rcpf(rsum16(e0));
    const float A1 = e1 * __builtin_amdgcn_rcpf(rsum16(e1));

    const float A0o = __shfl_xor(A0, 32);
    const float A1o = __shfl_xor(A1, 32);
    const bool loHalf = (lane < 32);

    float acc0 = 0.0f, acc1 = 0.0f;
#pragma unroll
    for (int k = 0; k < KN; ++k) {
        const float b0a = bcastlane(A0, rev4(k)), b0b = bcastlane(A0o, rev4(k));
        const float b1a = bcastlane(A1, rev4(k)), b1b = bcastlane(A1o, rev4(k));
        acc0 = fmaf(loHalf ? b0a : b0b, g[k].x, acc0);
        acc1 = fmaf(loHalf ? b1a : b1b, g[k].y, acc1);
    }
    float res = 0.5f * (acc0 + acc1) + bias[c];
    res = res > 0.0f ? res : expm1f(res);
    out[(size_t)tgt * 32 + c] = res;
}

// ---------------------------------------------------------------------------
// 4. Dual register-blocked MLP head: out = tanh(in@W2+b2)@W3+b3.
// ---------------------------------------------------------------------------
__global__ __launch_bounds__(256) void k_head2(
    const float* __restrict__ inA, const float* __restrict__ W3A,
    const float* __restrict__ b3A, float* __restrict__ outA,
    const float* __restrict__ inB, const float* __restrict__ W3B,
    const float* __restrict__ b3B, float* __restrict__ outB,
    const float* __restrict__ W2, const float* __restrict__ b2)
{
    __shared__ float xs[32][64];
    __shared__ float tmp[32][64];

    int bid = blockIdx.x;
    const bool second = bid >= 992;
    if (second) bid -= 992;

    const float* in  = second ? inB  : inA;
    const float* W3  = second ? W3B  : W3A;
    const float* b3  = second ? b3B  : b3A;
    float*       out = second ? outB : outA;

    const int c = threadIdx.x;
    const int g = threadIdx.y;
    const int tid = g * 64 + c;
    const int row0 = bid * 32;

    for (int idx = tid; idx < 32 * 16; idx += 256) {
        int r = idx >> 4, q = idx & 15;
        reinterpret_cast<float4*>(&xs[r][0])[q] =
            reinterpret_cast<const float4*>(in + (size_t)(row0 + r) * 64)[q];
    }
    __syncthreads();

    const int rb = g * 8;
    float acc[8];
    const float bc = b2[c];
#pragma unroll
    for (int r = 0; r < 8; ++r) acc[r] = bc;
#pragma unroll
    for (int i = 0; i < 64; ++i) {
        const float w2 = W2[i * 64 + c];
#pragma unroll
        for (int r = 0; r < 8; ++r)
            acc[r] = fmaf(xs[rb + r][i], w2, acc[r]);
    }
#pragma unroll
    for (int r = 0; r < 8; ++r) tmp[rb + r][c] = tanhf(acc[r]);

    const int cc = c < 50 ? c : 0;
    float a[8];
    const float b3c = b3[cc];
#pragma unroll
    for (int r = 0; r < 8; ++r) a[r] = b3c;
#pragma unroll
    for (int j = 0; j < 64; ++j) {
        const float w3 = W3[j * 50 + cc];
#pragma unroll
        for (int r = 0; r < 8; ++r)
            a[r] = fmaf(tmp[rb + r][j], w3, a[r]);
    }
    if (c < 50) {
#pragma unroll
        for (int r = 0; r < 8; ++r)
            out[(size_t)(row0 + rb + r) * 50 + c] = a[r];
    }
}

// ---------------------------------------------------------------------------
extern "C" void kernel_launch(void* const* d_in, const int* in_sizes, int n_in,
                              void* d_out, int out_size, void* d_ws, size_t ws_size,
                              hipStream_t stream)
{
    const float* x    = (const float*)d_in[0];
    const int*   edge = (const int*)d_in[1];

    const float *g1_Wl = (const float*)d_in[2],  *g1_bl = (const float*)d_in[3];
    const float *g1_Wr = (const float*)d_in[4],  *g1_br = (const float*)d_in[5];
    const float *g1_att= (const float*)d_in[6],  *g1_b  = (const float*)d_in[7];
    const float *g2_Wl = (const float*)d_in[8],  *g2_bl = (const float*)d_in[9];
    const float *g2_Wr = (const float*)d_in[10], *g2_br = (const float*)d_in[11];
    const float *g2_att= (const float*)d_in[12], *g2_b  = (const float*)d_in[13];
    const float *r1_Wl = (const float*)d_in[14], *r1_bl = (const float*)d_in[15];
    const float *r1_Wr = (const float*)d_in[16], *r1_br = (const float*)d_in[17];
    const float *r1_att= (const float*)d_in[18], *r1_b  = (const float*)d_in[19];
    const float *f1_Wl = (const float*)d_in[20], *f1_bl = (const float*)d_in[21];
    const float *f1_Wr = (const float*)d_in[22], *f1_br = (const float*)d_in[23];
    const float *f1_att= (const float*)d_in[24], *f1_b  = (const float*)d_in[25];
    const float *gru0_Wih = (const float*)d_in[26], *gru0_Whh = (const float*)d_in[27];
    const float *gru0_bih = (const float*)d_in[28], *gru0_bhh = (const float*)d_in[29];
    const float *gru1_Wih = (const float*)d_in[30], *gru1_Whh = (const float*)d_in[31];
    const float *gru1_bih = (const float*)d_in[32], *gru1_bhh = (const float*)d_in[33];
    const float *rec2_W = (const float*)d_in[34], *rec2_b = (const float*)d_in[35];
    const float *rec3_W = (const float*)d_in[36], *rec3_b = (const float*)d_in[37];
    const float *fore3_W= (const float*)d_in[38], *fore3_b= (const float*)d_in[39];

    // workspace layout
    char* ws = (char*)d_ws;
    int*   srcs = (int*)ws;                              // [32][1024][16] (2 MB)
    float* buf1 = (float*)(ws + (4u << 20));             // [32768,128]
    float* buf2 = buf1 + (size_t)32768 * 128;
    float* buf3 = buf2 + (size_t)32768 * 128;
    float* buf4 = buf3 + (size_t)32768 * 128;
    float* buf5 = buf4 + (size_t)32768 * 128;            // [32768,64]
    float* buf6 = buf5 + (size_t)32768 * 64;             // [32768,32]

    float* recon = (float*)d_out;                        // [31,1024,50]
    float* fore  = recon + (size_t)31 * 1024 * 50;       // [31,1024,50]
    float* E     = fore  + (size_t)31 * 1024 * 50;       // [32,1024,32]

    // 1. adjacency -> source lists
    k_srcs<<<Tt * 8, 1024, 0, stream>>>(edge, srcs);

    // 2. GAT g1 (64 -> 64): pair kernel, 16384 pairs
    k_lin2t<64, 128><<<1024, 256, 0, stream>>>(x, g1_Wl, g1_bl, g1_Wr, g1_br, buf1, buf2, 32768);
    k_gat64p<<<4096, 256, 0, stream>>>(buf1, buf2, srcs, g1_att, g1_b, buf5, 16384);

    // 3. GAT g2 (64 -> 32)
    k_lin2t<64, 64><<<512, 256, 0, stream>>>(buf5, g2_Wl, g2_bl, g2_Wr, g2_br, buf1, buf2, 32768);
    k_gat32<<<4096, 256, 0, stream>>>(buf1, buf2, srcs, g2_att, g2_b, buf6, 16384);

    // 4. GRU stack
    k_lin96<<<2048, dim3(96, 2), 0, stream>>>(buf6, gru0_Wih, gru0_bih, buf1);   // GI0
    k_gru1<<<512, 64, 0, stream>>>(buf1, gru0_Whh, gru0_bhh, buf5);              // E0
    k_lin96<<<2048, dim3(96, 2), 0, stream>>>(buf5, gru1_Wih, gru1_bih, buf2);   // GI1
    k_gru1<<<512, 64, 0, stream>>>(buf2, gru1_Whh, gru1_bhh, E);                 // E

    // 5. r1+f1 projections in one launch
    k_lin2td<<<1984, 256, 0, stream>>>(E,
        r1_Wl, r1_bl, r1_Wr, r1_br, buf1, buf2,
        f1_Wl, f1_bl, f1_Wr, f1_br, buf3, buf4);

    // 6. dual GAT bodies (one launch), then register-blocked dual head
    k_gat64p2<<<7936, 256, 0, stream>>>(
        buf1, buf2, srcs + (size_t)KN * Nn, r1_att, r1_b, buf5,
        buf3, buf4, srcs,                   f1_att, f1_b, buf6);   // buf6 free (E consumed)
    k_head2<<<1984, dim3(64, 4), 0, stream>>>(
        buf5, rec3_W, rec3_b, recon,
        buf6, fore3_W, fore3_b, fore,
        rec2_W, rec2_b);

    (void)in_sizes; (void)n_in; (void)out_size; (void)ws_size;
}

// Round 16
// 273.492 us; speedup vs baseline: 1.0610x; 1.0369x over previous
//
#include <hip/hip_runtime.h>
#include <math.h>

static constexpr int Tt = 32;
static constexpr int Nn = 1024;
static constexpr int KN = 16;   // K + self
static constexpr float LOG2E = 1.44269504f;

// ---------------------------------------------------------------------------
// Cross-lane primitives: DPP for xor1/xor2 (pure VALU), ds_swizzle otherwise.
// ---------------------------------------------------------------------------
template <int M>
__device__ __forceinline__ float lane_xor(float v) {
    if constexpr (M == 1)
        return __int_as_float(__builtin_amdgcn_mov_dpp(__float_as_int(v), 0xB1, 0xF, 0xF, true));
    else if constexpr (M == 2)
        return __int_as_float(__builtin_amdgcn_mov_dpp(__float_as_int(v), 0x4E, 0xF, 0xF, true));
    else
        return __shfl_xor(v, M);
}
__device__ __forceinline__ constexpr int rev4(int k) {
    return ((k & 1) << 3) | ((k & 2) << 1) | ((k & 4) >> 1) | ((k & 8) >> 3);
}
template <int NV, int M>
__device__ __forceinline__ void fstage(float* p, int lane) {
#pragma unroll
    for (int k2 = 0; k2 < NV / 2; ++k2) {
        float a_ = p[k2], b_ = p[k2 + NV / 2];
        float t_ = (lane & M) ? a_ : b_;
        float r_ = lane_xor<M>(t_);
        p[k2] = ((lane & M) ? b_ : a_) + r_;
    }
}
__device__ __forceinline__ float fold16(float* p, int lane) {
    fstage<16, 1>(p, lane); fstage<8, 2>(p, lane);
    fstage<4, 4>(p, lane);  fstage<2, 8>(p, lane);
    return p[0];
}
__device__ __forceinline__ float rsum16(float x) {
    x += lane_xor<1>(x); x += lane_xor<2>(x);
    x += lane_xor<4>(x); x += lane_xor<8>(x);
    return x;
}
// broadcast v from lane (lane&32)|rev4(k) (same half, rev4 slot)
__device__ __forceinline__ float bperm_alpha(float v, int pbase, int r4) {
    return __int_as_float(__builtin_amdgcn_ds_bpermute(pbase + (r4 << 2), __float_as_int(v)));
}
__device__ __forceinline__ float elu(float x) {
    return x > 0.0f ? x : (__builtin_amdgcn_exp2f(LOG2E * x) - 1.0f);
}

// ---------------------------------------------------------------------------
// 1. Recover source indices (order-free), layout srcs[t][n][16].
// ---------------------------------------------------------------------------
__global__ __launch_bounds__(1024) void k_srcs(const int* __restrict__ edge,
                                               int* __restrict__ srcs)
{
    __shared__ int cnt[128];
    const int t    = blockIdx.x >> 3;
    const int tgt0 = (blockIdx.x & 7) << 7;
    const int x = threadIdx.x & 31;
    const int y = threadIdx.x >> 5;
    if (threadIdx.x < 128) cnt[threadIdx.x] = 0;
    __syncthreads();

    const int c0 = 4 * x;
    const int s0 = y * 32;
    const int* e = edge + (size_t)t * Nn * Nn + tgt0 + c0;

    for (int i0 = 0; i0 < 32; i0 += 8) {
        int4 v[8];
#pragma unroll
        for (int j = 0; j < 8; ++j)
            v[j] = *reinterpret_cast<const int4*>(e + (size_t)(s0 + i0 + j) * Nn);
#pragma unroll
        for (int j = 0; j < 8; ++j) {
            const int s = s0 + i0 + j;
            if (v[j].x) { int sl = atomicAdd(&cnt[c0],     1); if (sl < KN - 1) srcs[((size_t)t * Nn + tgt0 + c0)     * KN + sl] = s; }
            if (v[j].y) { int sl = atomicAdd(&cnt[c0 + 1], 1); if (sl < KN - 1) srcs[((size_t)t * Nn + tgt0 + c0 + 1) * KN + sl] = s; }
            if (v[j].z) { int sl = atomicAdd(&cnt[c0 + 2], 1); if (sl < KN - 1) srcs[((size_t)t * Nn + tgt0 + c0 + 2) * KN + sl] = s; }
            if (v[j].w) { int sl = atomicAdd(&cnt[c0 + 3], 1); if (sl < KN - 1) srcs[((size_t)t * Nn + tgt0 + c0 + 3) * KN + sl] = s; }
        }
    }
    if (threadIdx.x < 128)
        srcs[((size_t)t * Nn + tgt0 + threadIdx.x) * KN + (KN - 1)] = tgt0 + threadIdx.x;
}

// ---------------------------------------------------------------------------
// 2. Register-blocked dual linear, HEAD-INTERLEAVED float2 output (c, c+HC).
// ---------------------------------------------------------------------------
template <int FI, int FO>
__global__ __launch_bounds__(256) void k_lin2t(
    const float* __restrict__ X,
    const float* __restrict__ Wl, const float* __restrict__ bl,
    const float* __restrict__ Wr, const float* __restrict__ br,
    float* __restrict__ Yl, float* __restrict__ Yr, int rows)
{
    constexpr int HC = FO / 2;
    constexpr int RG = 256 / HC;
    constexpr int R  = 8;
    constexpr int BR = RG * R;
    constexpr int F4 = FI / 4;
    __shared__ float xs[BR][FI];

    const int tid  = threadIdx.x;
    const int c    = tid % HC;
    const int g    = tid / HC;
    const int row0 = blockIdx.x * BR;

#pragma unroll
    for (int idx = tid; idx < BR * F4; idx += 256) {
        int r = idx / F4, q = idx % F4;
        reinterpret_cast<float4*>(&xs[r][0])[q] =
            reinterpret_cast<const float4*>(X + (size_t)(row0 + r) * FI)[q];
    }
    __syncthreads();

    float al0[R], al1[R], ar0[R], ar1[R];
    const float bl0 = bl[c], bl1 = bl[c + HC], br0 = br[c], br1 = br[c + HC];
#pragma unroll
    for (int r = 0; r < R; ++r) { al0[r] = bl0; al1[r] = bl1; ar0[r] = br0; ar1[r] = br1; }

    const int rb = g * R;
#pragma unroll
    for (int i0 = 0; i0 < FI; i0 += 4) {
        float4 xv[R];
#pragma unroll
        for (int r = 0; r < R; ++r)
            xv[r] = *reinterpret_cast<const float4*>(&xs[rb + r][i0]);
#pragma unroll
        for (int j = 0; j < 4; ++j) {
            const float wl0 = Wl[(i0 + j) * FO + c];
            const float wl1 = Wl[(i0 + j) * FO + c + HC];
            const float wr0 = Wr[(i0 + j) * FO + c];
            const float wr1 = Wr[(i0 + j) * FO + c + HC];
#pragma unroll
            for (int r = 0; r < R; ++r) {
                const float xx = (&xv[r].x)[j];
                al0[r] = fmaf(xx, wl0, al0[r]);
                al1[r] = fmaf(xx, wl1, al1[r]);
                ar0[r] = fmaf(xx, wr0, ar0[r]);
                ar1[r] = fmaf(xx, wr1, ar1[r]);
            }
        }
    }
#pragma unroll
    for (int r = 0; r < R; ++r) {
        const size_t ro = (size_t)(row0 + rb + r) * FO;
        reinterpret_cast<float2*>(Yl + ro)[c] = make_float2(al0[r], al1[r]);
        reinterpret_cast<float2*>(Yr + ro)[c] = make_float2(ar0[r], ar1[r]);
    }
}

// ---------------------------------------------------------------------------
// 2m. Merged r1+f1 projection (one launch, pointer select).
// ---------------------------------------------------------------------------
__global__ __launch_bounds__(256) void k_lin2td(
    const float* __restrict__ E,
    const float* __restrict__ WlA, const float* __restrict__ blA,
    const float* __restrict__ WrA, const float* __restrict__ brA,
    float* __restrict__ YlA, float* __restrict__ YrA,
    const float* __restrict__ WlB, const float* __restrict__ blB,
    const float* __restrict__ WrB, const float* __restrict__ brB,
    float* __restrict__ YlB, float* __restrict__ YrB)
{
    constexpr int FI = 32, FO = 128, HC = 64, R = 8, BR = 32, F4 = FI / 4;
    __shared__ float xs[BR][FI];

    int bid = blockIdx.x;
    const bool second = bid >= 992;
    if (second) bid -= 992;

    const float* X  = second ? E   : (E + (size_t)Nn * FI);
    const float* Wl = second ? WlB : WlA;
    const float* bl = second ? blB : blA;
    const float* Wr = second ? WrB : WrA;
    const float* br = second ? brB : brA;
    float* Yl = second ? YlB : YlA;
    float* Yr = second ? YrB : YrA;

    const int tid  = threadIdx.x;
    const int c    = tid % HC;
    const int g    = tid / HC;
    const int row0 = bid * BR;

#pragma unroll
    for (int idx = tid; idx < BR * F4; idx += 256) {
        int r = idx / F4, q = idx % F4;
        reinterpret_cast<float4*>(&xs[r][0])[q] =
            reinterpret_cast<const float4*>(X + (size_t)(row0 + r) * FI)[q];
    }
    __syncthreads();

    float al0[R], al1[R], ar0[R], ar1[R];
    const float bl0 = bl[c], bl1 = bl[c + HC], br0 = br[c], br1 = br[c + HC];
#pragma unroll
    for (int r = 0; r < R; ++r) { al0[r] = bl0; al1[r] = bl1; ar0[r] = br0; ar1[r] = br1; }

    const int rb = g * R;
#pragma unroll
    for (int i0 = 0; i0 < FI; i0 += 4) {
        float4 xv[R];
#pragma unroll
        for (int r = 0; r < R; ++r)
            xv[r] = *reinterpret_cast<const float4*>(&xs[rb + r][i0]);
#pragma unroll
        for (int j = 0; j < 4; ++j) {
            const float wl0 = Wl[(i0 + j) * FO + c];
            const float wl1 = Wl[(i0 + j) * FO + c + HC];
            const float wr0 = Wr[(i0 + j) * FO + c];
            const float wr1 = Wr[(i0 + j) * FO + c + HC];
#pragma unroll
            for (int r = 0; r < R; ++r) {
                const float xx = (&xv[r].x)[j];
                al0[r] = fmaf(xx, wl0, al0[r]);
                al1[r] = fmaf(xx, wl1, al1[r]);
                ar0[r] = fmaf(xx, wr0, ar0[r]);
                ar1[r] = fmaf(xx, wr1, ar1[r]);
            }
        }
    }
#pragma unroll
    for (int r = 0; r < R; ++r) {
        const size_t ro = (size_t)(row0 + rb + r) * FO;
        reinterpret_cast<float2*>(Yl + ro)[c] = make_float2(al0[r], al1[r]);
        reinterpret_cast<float2*>(Yr + ro)[c] = make_float2(ar0[r], ar1[r]);
    }
}

// ---------------------------------------------------------------------------
// 2b. Single linear to 96 cols (GRU input gates): Y = X@W^T + b.
// ---------------------------------------------------------------------------
__global__ __launch_bounds__(192) void k_lin96(
    const float* __restrict__ X, const float* __restrict__ W,
    const float* __restrict__ b, float* __restrict__ Y)
{
    __shared__ float wT[32 * 97];
    __shared__ float xs[16][32];

    const int tid = threadIdx.y * 96 + threadIdx.x;
    const int row0 = blockIdx.x * 16;

    for (int idx = tid; idx < 3072; idx += 192) {
        int c = idx >> 5, i = idx & 31;
        wT[i * 97 + c] = W[idx];
    }
    for (int idx = tid; idx < 128; idx += 192)
        reinterpret_cast<float4*>(xs)[idx] =
            reinterpret_cast<const float4*>(X + (size_t)row0 * 32)[idx];
    __syncthreads();

    const int c  = threadIdx.x;
    const int rb = threadIdx.y * 8;
    float acc[8];
    const float bc = b[c];
#pragma unroll
    for (int r = 0; r < 8; ++r) acc[r] = bc;

#pragma unroll
    for (int i = 0; i < 32; ++i) {
        const float w = wT[i * 97 + c];
#pragma unroll
        for (int r = 0; r < 8; ++r)
            acc[r] = fmaf(xs[rb + r][i], w, acc[r]);
    }
#pragma unroll
    for (int r = 0; r < 8; ++r)
        Y[(size_t)(row0 + rb + r) * 96 + c] = acc[r];
}

// ---------------------------------------------------------------------------
// 2c. Serial GRU layer: register weights, shfl broadcast, gi prefetch,
//     exp2-based sigmoid/tanh (shorter serial chain).
// ---------------------------------------------------------------------------
__global__ __launch_bounds__(64) void k_gru1(
    const float* __restrict__ gi, const float* __restrict__ Whh,
    const float* __restrict__ bhh, float* __restrict__ E)
{
    const int d    = threadIdx.x & 31;
    const int node = blockIdx.x * 2 + (threadIdx.x >> 5);

    float wr_[32], wz_[32], wn_[32];
#pragma unroll
    for (int q = 0; q < 8; ++q) {
        *reinterpret_cast<float4*>(&wr_[q * 4]) =
            reinterpret_cast<const float4*>(Whh + (size_t)d * 32)[q];
        *reinterpret_cast<float4*>(&wz_[q * 4]) =
            reinterpret_cast<const float4*>(Whh + (size_t)(32 + d) * 32)[q];
        *reinterpret_cast<float4*>(&wn_[q * 4]) =
            reinterpret_cast<const float4*>(Whh + (size_t)(64 + d) * 32)[q];
    }
    const float br_ = bhh[d], bz_ = bhh[32 + d], bn_ = bhh[64 + d];

    size_t base = (size_t)node * 96 + d;
    float gr = gi[base], gz = gi[base + 32], gn = gi[base + 64];

    float h = 0.0f;
    for (int t = 0; t < Tt; ++t) {
        float grn = 0.f, gzn = 0.f, gnn = 0.f;
        if (t < Tt - 1) {
            const size_t nb = ((size_t)(t + 1) * Nn + node) * 96 + d;
            grn = gi[nb]; gzn = gi[nb + 32]; gnn = gi[nb + 64];
        }
        float ar = br_, az = bz_, an = bn_;
#pragma unroll
        for (int i = 0; i < 32; ++i) {
            const float hv = __shfl(h, i, 32);
            ar = fmaf(wr_[i], hv, ar);
            az = fmaf(wz_[i], hv, az);
            an = fmaf(wn_[i], hv, an);
        }
        const float r = __builtin_amdgcn_rcpf(1.0f + __builtin_amdgcn_exp2f(-LOG2E * (gr + ar)));
        const float z = __builtin_amdgcn_rcpf(1.0f + __builtin_amdgcn_exp2f(-LOG2E * (gz + az)));
        const float xx = gn + r * an;
        const float nn2 = 1.0f - 2.0f * __builtin_amdgcn_rcpf(1.0f + __builtin_amdgcn_exp2f((2.0f * LOG2E) * xx));
        h = (1.0f - z) * nn2 + z * h;
        E[((size_t)t * Nn + node) * 32 + d] = h;
        gr = grn; gz = gzn; gn = gnn;
    }
}

// ---------------------------------------------------------------------------
// Shared GATv2 C=64 PAIR body: TWO targets per wave (one per 32-lane half).
// No max-subtract softmax (logits are O(1)); exp via v_exp_f32; alpha
// broadcast via single ds_bpermute per (k, head).
// ---------------------------------------------------------------------------
__device__ __forceinline__ void gat64_pair_body(
    const float* __restrict__ gl, const float* __restrict__ gr,
    const int* __restrict__ srcs, const float* __restrict__ att,
    const float* __restrict__ bias, int wv, int lane,
    float* __restrict__ out)
{
    const int tgt = 2 * wv + (lane >> 5);
    const int t = tgt >> 10;
    const int n = tgt & (Nn - 1);
    const int c = lane & 31;

    const float2* grrow = reinterpret_cast<const float2*>(gr) + (size_t)tgt * 64;
    const float2 grl0 = grrow[c];
    const float2 grl1 = grrow[32 + c];
    const float a00 = att[c],      a01 = att[32 + c];
    const float a10 = att[64 + c], a11 = att[96 + c];

    const int4* sp = reinterpret_cast<const int4*>(srcs + ((size_t)t * Nn + n) * KN);
    const int4 sA = sp[0], sB = sp[1], sC = sp[2], sD = sp[3];
    int s[KN] = {sA.x, sA.y, sA.z, sA.w, sB.x, sB.y, sB.z, sB.w,
                 sC.x, sC.y, sC.z, sC.w, sD.x, sD.y, sD.z, sD.w};

    const float2* glt = reinterpret_cast<const float2*>(gl) + ((size_t)t * Nn * 64);

    float2 g0[KN], g1[KN];
    float p0[KN], p1[KN];
#pragma unroll
    for (int k = 0; k < KN; ++k) {
        const unsigned ro = (unsigned)(s[k] << 6);
        g0[k] = glt[ro | c];
        g1[k] = glt[ro | (32 + c)];
        float e00 = g0[k].x + grl0.x; e00 = fmaxf(e00, 0.2f * e00);
        float e01 = g1[k].x + grl1.x; e01 = fmaxf(e01, 0.2f * e01);
        float e10 = g0[k].y + grl0.y; e10 = fmaxf(e10, 0.2f * e10);
        float e11 = g1[k].y + grl1.y; e11 = fmaxf(e11, 0.2f * e11);
        p0[k] = fmaf(e01, a01, e00 * a00);
        p1[k] = fmaf(e11, a11, e10 * a10);
    }
    float lo0 = fold16(p0, lane); lo0 += lane_xor<16>(lo0);
    float lo1 = fold16(p1, lane); lo1 += lane_xor<16>(lo1);

    // softmax without max-subtract (logits O(1); fp32-safe)
    const float e0 = __builtin_amdgcn_exp2f(LOG2E * lo0);
    const float e1 = __builtin_amdgcn_exp2f(LOG2E * lo1);
    const float A0 = e0 * __builtin_amdgcn_rcpf(rsum16(e0));
    const float A1 = e1 * __builtin_amdgcn_rcpf(rsum16(e1));

    const int pbase = (lane & 32) << 2;       // bpermute byte base (same half)
    float acc00 = 0.0f, acc01 = 0.0f, acc10 = 0.0f, acc11 = 0.0f;
#pragma unroll
    for (int k = 0; k < KN; ++k) {
        const float b0 = bperm_alpha(A0, pbase, rev4(k));
        const float b1 = bperm_alpha(A1, pbase, rev4(k));
        acc00 = fmaf(b0, g0[k].x, acc00);
        acc01 = fmaf(b0, g1[k].x, acc01);
        acc10 = fmaf(b1, g0[k].y, acc10);
        acc11 = fmaf(b1, g1[k].y, acc11);
    }
    float r0 = 0.5f * (acc00 + acc10) + bias[c];
    float r1 = 0.5f * (acc01 + acc11) + bias[32 + c];
    out[(size_t)tgt * 64 + c]      = elu(r0);
    out[(size_t)tgt * 64 + 32 + c] = elu(r1);
}

// ---------------------------------------------------------------------------
// 3. GATv2 C=64 pair kernel (g1).
// ---------------------------------------------------------------------------
__global__ __launch_bounds__(256, 3) void k_gat64p(
    const float* __restrict__ gl, const float* __restrict__ gr,
    const int* __restrict__ srcs, const float* __restrict__ att,
    const float* __restrict__ bias, float* __restrict__ out, int pairs)
{
    const int lane = threadIdx.x & 63;
    const int w = threadIdx.x >> 6;
    const int gridB = pairs >> 2;
    const int chunk = gridB >> 3;
    const int bid = blockIdx.x;
    const int lb = (bid & 7) * chunk + (bid >> 3);
    const int wv = lb * 4 + w;
    gat64_pair_body(gl, gr, srcs, att, bias, wv, lane, out);
}

// ---------------------------------------------------------------------------
// 3d. Dual-path GATv2 C=64 pair kernel (r1 + f1 tails in one launch).
// ---------------------------------------------------------------------------
__global__ __launch_bounds__(256, 3) void k_gat64p2(
    const float* __restrict__ glA, const float* __restrict__ grA,
    const int* __restrict__ srcsA, const float* __restrict__ attA,
    const float* __restrict__ biasA, float* __restrict__ outA,
    const float* __restrict__ glB, const float* __restrict__ grB,
    const int* __restrict__ srcsB, const float* __restrict__ attB,
    const float* __restrict__ biasB, float* __restrict__ outB)
{
    constexpr int pairs = (Tt - 1) * Nn / 2;   // 15872
    constexpr int gridH = pairs >> 2;           // 3968
    constexpr int chunk = gridH >> 3;           // 496

    int bid = blockIdx.x;
    const bool second = bid >= gridH;
    if (second) bid -= gridH;

    const float* gl   = second ? glB   : glA;
    const float* gr   = second ? grB   : grA;
    const int*   srcs = second ? srcsB : srcsA;
    const float* att  = second ? attB  : attA;
    const float* bias = second ? biasB : biasA;
    float*       out  = second ? outB  : outA;

    const int lane = threadIdx.x & 63;
    const int w = threadIdx.x >> 6;
    const int lb = (bid & 7) * chunk + (bid >> 3);
    const int wv = lb * 4 + w;
    gat64_pair_body(gl, gr, srcs, att, bias, wv, lane, out);
}

// ---------------------------------------------------------------------------
// 3b. GATv2 C=32: two targets per wave, same softmax/bpermute scheme.
// ---------------------------------------------------------------------------
__global__ __launch_bounds__(256, 4) void k_gat32(
    const float* __restrict__ gl, const float* __restrict__ gr,
    const int* __restrict__ srcs, const float* __restrict__ att,
    const float* __restrict__ bias, float* __restrict__ out, int waves)
{
    const int lane = threadIdx.x & 63;
    const int w = threadIdx.x >> 6;
    const int gridB = waves >> 2;
    const int chunk = gridB >> 3;
    const int bid = blockIdx.x;
    const int lb = (bid & 7) * chunk + (bid >> 3);
    const int wv = lb * 4 + w;
    const int tgt = 2 * wv + (lane >> 5);
    const int t = tgt >> 10;
    const int n = tgt & (Nn - 1);
    const int c = lane & 31;

    const float2 grl = reinterpret_cast<const float2*>(gr + (size_t)tgt * 64)[c];
    const float a0 = att[c], a1 = att[32 + c];

    const int4* sp = reinterpret_cast<const int4*>(srcs + ((size_t)t * Nn + n) * KN);
    const int4 sA = sp[0], sB = sp[1], sC = sp[2], sD = sp[3];
    int s[KN] = {sA.x, sA.y, sA.z, sA.w, sB.x, sB.y, sB.z, sB.w,
                 sC.x, sC.y, sC.z, sC.w, sD.x, sD.y, sD.z, sD.w};

    const float2* glt = reinterpret_cast<const float2*>(gl) + ((size_t)t * Nn * 32);

    float2 g[KN];
    float p0[KN], p1[KN];
#pragma unroll
    for (int k = 0; k < KN; ++k) {
        g[k] = glt[(unsigned)((s[k] << 5) | c)];
        float e0 = g[k].x + grl.x; e0 = fmaxf(e0, 0.2f * e0);
        float e1 = g[k].y + grl.y; e1 = fmaxf(e1, 0.2f * e1);
        p0[k] = e0 * a0; p1[k] = e1 * a1;
    }
    float lo0 = fold16(p0, lane); lo0 += lane_xor<16>(lo0);
    float lo1 = fold16(p1, lane); lo1 += lane_xor<16>(lo1);

    const float e0 = __builtin_amdgcn_exp2f(LOG2E * lo0);
    const float e1 = __builtin_amdgcn_exp2f(LOG2E * lo1);
    const float A0 = e0 * __builtin_amdgcn_rcpf(rsum16(e0));
    const float A1 = e1 * __builtin_amdgcn_rcpf(rsum16(e1));

    const int pbase = (lane & 32) << 2;
    float acc0 = 0.0f, acc1 = 0.0f;
#pragma unroll
    for (int k = 0; k < KN; ++k) {
        const float b0 = bperm_alpha(A0, pbase, rev4(k));
        const float b1 = bperm_alpha(A1, pbase, rev4(k));
        acc0 = fmaf(b0, g[k].x, acc0);
        acc1 = fmaf(b1, g[k].y, acc1);
    }
    float res = 0.5f * (acc0 + acc1) + bias[c];
    out[(size_t)tgt * 32 + c] = elu(res);
}

// ---------------------------------------------------------------------------
// 4. Dual register-blocked MLP head: out = tanh(in@W2+b2)@W3+b3.
// ---------------------------------------------------------------------------
__global__ __launch_bounds__(256) void k_head2(
    const float* __restrict__ inA, const float* __restrict__ W3A,
    const float* __restrict__ b3A, float* __restrict__ outA,
    const float* __restrict__ inB, const float* __restrict__ W3B,
    const float* __restrict__ b3B, float* __restrict__ outB,
    const float* __restrict__ W2, const float* __restrict__ b2)
{
    __shared__ float xs[32][64];
    __shared__ float tmp[32][64];

    int bid = blockIdx.x;
    const bool second = bid >= 992;
    if (second) bid -= 992;

    const float* in  = second ? inB  : inA;
    const float* W3  = second ? W3B  : W3A;
    const float* b3  = second ? b3B  : b3A;
    float*       out = second ? outB : outA;

    const int c = threadIdx.x;
    const int g = threadIdx.y;
    const int tid = g * 64 + c;
    const int row0 = bid * 32;

    for (int idx = tid; idx < 32 * 16; idx += 256) {
        int r = idx >> 4, q = idx & 15;
        reinterpret_cast<float4*>(&xs[r][0])[q] =
            reinterpret_cast<const float4*>(in + (size_t)(row0 + r) * 64)[q];
    }
    __syncthreads();

    const int rb = g * 8;
    float acc[8];
    const float bc = b2[c];
#pragma unroll
    for (int r = 0; r < 8; ++r) acc[r] = bc;
#pragma unroll
    for (int i = 0; i < 64; ++i) {
        const float w2 = W2[i * 64 + c];
#pragma unroll
        for (int r = 0; r < 8; ++r)
            acc[r] = fmaf(xs[rb + r][i], w2, acc[r]);
    }
#pragma unroll
    for (int r = 0; r < 8; ++r) tmp[rb + r][c] = tanhf(acc[r]);

    const int cc = c < 50 ? c : 0;
    float a[8];
    const float b3c = b3[cc];
#pragma unroll
    for (int r = 0; r < 8; ++r) a[r] = b3c;
#pragma unroll
    for (int j = 0; j < 64; ++j) {
        const float w3 = W3[j * 50 + cc];
#pragma unroll
        for (int r = 0; r < 8; ++r)
            a[r] = fmaf(tmp[rb + r][j], w3, a[r]);
    }
    if (c < 50) {
#pragma unroll
        for (int r = 0; r < 8; ++r)
            out[(size_t)(row0 + rb + r) * 50 + c] = a[r];
    }
}

// ---------------------------------------------------------------------------
extern "C" void kernel_launch(void* const* d_in, const int* in_sizes, int n_in,
                              void* d_out, int out_size, void* d_ws, size_t ws_size,
                              hipStream_t stream)
{
    const float* x    = (const float*)d_in[0];
    const int*   edge = (const int*)d_in[1];

    const float *g1_Wl = (const float*)d_in[2],  *g1_bl = (const float*)d_in[3];
    const float *g1_Wr = (const float*)d_in[4],  *g1_br = (const float*)d_in[5];
    const float *g1_att= (const float*)d_in[6],  *g1_b  = (const float*)d_in[7];
    const float *g2_Wl = (const float*)d_in[8],  *g2_bl = (const float*)d_in[9];
    const float *g2_Wr = (const float*)d_in[10], *g2_br = (const float*)d_in[11];
    const float *g2_att= (const float*)d_in[12], *g2_b  = (const float*)d_in[13];
    const float *r1_Wl = (const float*)d_in[14], *r1_bl = (const float*)d_in[15];
    const float *r1_Wr = (const float*)d_in[16], *r1_br = (const float*)d_in[17];
    const float *r1_att= (const float*)d_in[18], *r1_b  = (const float*)d_in[19];
    const float *f1_Wl = (const float*)d_in[20], *f1_bl = (const float*)d_in[21];
    const float *f1_Wr = (const float*)d_in[22], *f1_br = (const float*)d_in[23];
    const float *f1_att= (const float*)d_in[24], *f1_b  = (const float*)d_in[25];
    const float *gru0_Wih = (const float*)d_in[26], *gru0_Whh = (const float*)d_in[27];
    const float *gru0_bih = (const float*)d_in[28], *gru0_bhh = (const float*)d_in[29];
    const float *gru1_Wih = (const float*)d_in[30], *gru1_Whh = (const float*)d_in[31];
    const float *gru1_bih = (const float*)d_in[32], *gru1_bhh = (const float*)d_in[33];
    const float *rec2_W = (const float*)d_in[34], *rec2_b = (const float*)d_in[35];
    const float *rec3_W = (const float*)d_in[36], *rec3_b = (const float*)d_in[37];
    const float *fore3_W= (const float*)d_in[38], *fore3_b= (const float*)d_in[39];

    // workspace layout
    char* ws = (char*)d_ws;
    int*   srcs = (int*)ws;                              // [32][1024][16] (2 MB)
    float* buf1 = (float*)(ws + (4u << 20));             // [32768,128]
    float* buf2 = buf1 + (size_t)32768 * 128;
    float* buf3 = buf2 + (size_t)32768 * 128;
    float* buf4 = buf3 + (size_t)32768 * 128;
    float* buf5 = buf4 + (size_t)32768 * 128;            // [32768,64]
    float* buf6 = buf5 + (size_t)32768 * 64;             // [32768,32]

    float* recon = (float*)d_out;                        // [31,1024,50]
    float* fore  = recon + (size_t)31 * 1024 * 50;       // [31,1024,50]
    float* E     = fore  + (size_t)31 * 1024 * 50;       // [32,1024,32]

    // 1. adjacency -> source lists
    k_srcs<<<Tt * 8, 1024, 0, stream>>>(edge, srcs);

    // 2. GAT g1 (64 -> 64): pair kernel, 16384 pairs
    k_lin2t<64, 128><<<1024, 256, 0, stream>>>(x, g1_Wl, g1_bl, g1_Wr, g1_br, buf1, buf2, 32768);
    k_gat64p<<<4096, 256, 0, stream>>>(buf1, buf2, srcs, g1_att, g1_b, buf5, 16384);

    // 3. GAT g2 (64 -> 32)
    k_lin2t<64, 64><<<512, 256, 0, stream>>>(buf5, g2_Wl, g2_bl, g2_Wr, g2_br, buf1, buf2, 32768);
    k_gat32<<<4096, 256, 0, stream>>>(buf1, buf2, srcs, g2_att, g2_b, buf6, 16384);

    // 4. GRU stack
    k_lin96<<<2048, dim3(96, 2), 0, stream>>>(buf6, gru0_Wih, gru0_bih, buf1);   // GI0
    k_gru1<<<512, 64, 0, stream>>>(buf1, gru0_Whh, gru0_bhh, buf5);              // E0
    k_lin96<<<2048, dim3(96, 2), 0, stream>>>(buf5, gru1_Wih, gru1_bih, buf2);   // GI1
    k_gru1<<<512, 64, 0, stream>>>(buf2, gru1_Whh, gru1_bhh, E);                 // E

    // 5. r1+f1 projections in one launch
    k_lin2td<<<1984, 256, 0, stream>>>(E,
        r1_Wl, r1_bl, r1_Wr, r1_br, buf1, buf2,
        f1_Wl, f1_bl, f1_Wr, f1_br, buf3, buf4);

    // 6. dual GAT bodies (one launch), then register-blocked dual head
    k_gat64p2<<<7936, 256, 0, stream>>>(
        buf1, buf2, srcs + (size_t)KN * Nn, r1_att, r1_b, buf5,
        buf3, buf4, srcs,                   f1_att, f1_b, buf6);
    k_head2<<<1984, dim3(64, 4), 0, stream>>>(
        buf5, rec3_W, rec3_b, recon,
        buf6, fore3_W, fore3_b, fore,
        rec2_W, rec2_b);

    (void)in_sizes; (void)n_in; (void)out_size; (void)ws_size;
}

// Round 17
// 240.497 us; speedup vs baseline: 1.2065x; 1.1372x over previous
//
#include <hip/hip_runtime.h>
#include <math.h>

static constexpr int Tt = 32;
static constexpr int Nn = 1024;
static constexpr int KN = 16;   // K + self
static constexpr float LOG2E = 1.44269504f;

// ---------------------------------------------------------------------------
// Cross-lane primitives: DPP for xor1/xor2 (pure VALU), ds_swizzle otherwise.
// ---------------------------------------------------------------------------
template <int M>
__device__ __forceinline__ float lane_xor(float v) {
    if constexpr (M == 1)
        return __int_as_float(__builtin_amdgcn_mov_dpp(__float_as_int(v), 0xB1, 0xF, 0xF, true));
    else if constexpr (M == 2)
        return __int_as_float(__builtin_amdgcn_mov_dpp(__float_as_int(v), 0x4E, 0xF, 0xF, true));
    else
        return __shfl_xor(v, M);
}
__device__ __forceinline__ constexpr int rev4(int k) {
    return ((k & 1) << 3) | ((k & 2) << 1) | ((k & 4) >> 1) | ((k & 8) >> 3);
}
template <int NV, int M>
__device__ __forceinline__ void fstage(float* p, int lane) {
#pragma unroll
    for (int k2 = 0; k2 < NV / 2; ++k2) {
        float a_ = p[k2], b_ = p[k2 + NV / 2];
        float t_ = (lane & M) ? a_ : b_;
        float r_ = lane_xor<M>(t_);
        p[k2] = ((lane & M) ? b_ : a_) + r_;
    }
}
__device__ __forceinline__ float fold16(float* p, int lane) {
    fstage<16, 1>(p, lane); fstage<8, 2>(p, lane);
    fstage<4, 4>(p, lane);  fstage<2, 8>(p, lane);
    return p[0];
}
__device__ __forceinline__ float rsum16(float x) {
    x += lane_xor<1>(x); x += lane_xor<2>(x);
    x += lane_xor<4>(x); x += lane_xor<8>(x);
    return x;
}
__device__ __forceinline__ float bperm_alpha(float v, int pbase, int r4) {
    return __int_as_float(__builtin_amdgcn_ds_bpermute(pbase + (r4 << 2), __float_as_int(v)));
}
__device__ __forceinline__ float elu(float x) {
    return x > 0.0f ? x : (__builtin_amdgcn_exp2f(LOG2E * x) - 1.0f);
}
__device__ __forceinline__ float fast_tanh(float x) {
    return 1.0f - 2.0f * __builtin_amdgcn_rcpf(1.0f + __builtin_amdgcn_exp2f((2.0f * LOG2E) * x));
}

// ---------------------------------------------------------------------------
// 1. Recover source indices (order-free), layout srcs[t][n][16].
//    512 blocks (t x 16 stripes of 64 targets) x 1024 thr; low VGPR so
//    2 blocks/CU co-reside (32 waves/CU of loads in flight).
// ---------------------------------------------------------------------------
__global__ __launch_bounds__(1024) void k_srcs(const int* __restrict__ edge,
                                               int* __restrict__ srcs)
{
    __shared__ int cnt[64];
    const int t    = blockIdx.x >> 4;          // 0..31
    const int tgt0 = (blockIdx.x & 15) << 6;   // 0,64,...,960
    const int x = threadIdx.x & 15;            // int4 group -> 4 targets (64 total)
    const int y = threadIdx.x >> 4;            // s-group 0..63 (16 sources each)
    if (threadIdx.x < 64) cnt[threadIdx.x] = 0;
    __syncthreads();

    const int c0 = 4 * x;
    const int s0 = y * 16;
    const int* e = edge + (size_t)t * Nn * Nn + tgt0 + c0;

    for (int i0 = 0; i0 < 16; i0 += 8) {
        int4 v[8];
#pragma unroll
        for (int j = 0; j < 8; ++j)
            v[j] = *reinterpret_cast<const int4*>(e + (size_t)(s0 + i0 + j) * Nn);
#pragma unroll
        for (int j = 0; j < 8; ++j) {
            const int s = s0 + i0 + j;
            if (v[j].x) { int sl = atomicAdd(&cnt[c0],     1); if (sl < KN - 1) srcs[((size_t)t * Nn + tgt0 + c0)     * KN + sl] = s; }
            if (v[j].y) { int sl = atomicAdd(&cnt[c0 + 1], 1); if (sl < KN - 1) srcs[((size_t)t * Nn + tgt0 + c0 + 1) * KN + sl] = s; }
            if (v[j].z) { int sl = atomicAdd(&cnt[c0 + 2], 1); if (sl < KN - 1) srcs[((size_t)t * Nn + tgt0 + c0 + 2) * KN + sl] = s; }
            if (v[j].w) { int sl = atomicAdd(&cnt[c0 + 3], 1); if (sl < KN - 1) srcs[((size_t)t * Nn + tgt0 + c0 + 3) * KN + sl] = s; }
        }
    }
    if (threadIdx.x < 64)
        srcs[((size_t)t * Nn + tgt0 + threadIdx.x) * KN + (KN - 1)] = tgt0 + threadIdx.x;
}

// ---------------------------------------------------------------------------
// 2. Register-blocked dual linear, HEAD-INTERLEAVED float2 output (c, c+HC).
// ---------------------------------------------------------------------------
template <int FI, int FO>
__global__ __launch_bounds__(256) void k_lin2t(
    const float* __restrict__ X,
    const float* __restrict__ Wl, const float* __restrict__ bl,
    const float* __restrict__ Wr, const float* __restrict__ br,
    float* __restrict__ Yl, float* __restrict__ Yr, int rows)
{
    constexpr int HC = FO / 2;
    constexpr int RG = 256 / HC;
    constexpr int R  = 8;
    constexpr int BR = RG * R;
    constexpr int F4 = FI / 4;
    __shared__ float xs[BR][FI];

    const int tid  = threadIdx.x;
    const int c    = tid % HC;
    const int g    = tid / HC;
    const int row0 = blockIdx.x * BR;

#pragma unroll
    for (int idx = tid; idx < BR * F4; idx += 256) {
        int r = idx / F4, q = idx % F4;
        reinterpret_cast<float4*>(&xs[r][0])[q] =
            reinterpret_cast<const float4*>(X + (size_t)(row0 + r) * FI)[q];
    }
    __syncthreads();

    float al0[R], al1[R], ar0[R], ar1[R];
    const float bl0 = bl[c], bl1 = bl[c + HC], br0 = br[c], br1 = br[c + HC];
#pragma unroll
    for (int r = 0; r < R; ++r) { al0[r] = bl0; al1[r] = bl1; ar0[r] = br0; ar1[r] = br1; }

    const int rb = g * R;
#pragma unroll
    for (int i0 = 0; i0 < FI; i0 += 4) {
        float4 xv[R];
#pragma unroll
        for (int r = 0; r < R; ++r)
            xv[r] = *reinterpret_cast<const float4*>(&xs[rb + r][i0]);
#pragma unroll
        for (int j = 0; j < 4; ++j) {
            const float wl0 = Wl[(i0 + j) * FO + c];
            const float wl1 = Wl[(i0 + j) * FO + c + HC];
            const float wr0 = Wr[(i0 + j) * FO + c];
            const float wr1 = Wr[(i0 + j) * FO + c + HC];
#pragma unroll
            for (int r = 0; r < R; ++r) {
                const float xx = (&xv[r].x)[j];
                al0[r] = fmaf(xx, wl0, al0[r]);
                al1[r] = fmaf(xx, wl1, al1[r]);
                ar0[r] = fmaf(xx, wr0, ar0[r]);
                ar1[r] = fmaf(xx, wr1, ar1[r]);
            }
        }
    }
#pragma unroll
    for (int r = 0; r < R; ++r) {
        const size_t ro = (size_t)(row0 + rb + r) * FO;
        reinterpret_cast<float2*>(Yl + ro)[c] = make_float2(al0[r], al1[r]);
        reinterpret_cast<float2*>(Yr + ro)[c] = make_float2(ar0[r], ar1[r]);
    }
}

// ---------------------------------------------------------------------------
// 2m. Merged r1+f1 projection (one launch, pointer select).
// ---------------------------------------------------------------------------
__global__ __launch_bounds__(256) void k_lin2td(
    const float* __restrict__ E,
    const float* __restrict__ WlA, const float* __restrict__ blA,
    const float* __restrict__ WrA, const float* __restrict__ brA,
    float* __restrict__ YlA, float* __restrict__ YrA,
    const float* __restrict__ WlB, const float* __restrict__ blB,
    const float* __restrict__ WrB, const float* __restrict__ brB,
    float* __restrict__ YlB, float* __restrict__ YrB)
{
    constexpr int FI = 32, FO = 128, HC = 64, R = 8, BR = 32, F4 = FI / 4;
    __shared__ float xs[BR][FI];

    int bid = blockIdx.x;
    const bool second = bid >= 992;
    if (second) bid -= 992;

    const float* X  = second ? E   : (E + (size_t)Nn * FI);
    const float* Wl = second ? WlB : WlA;
    const float* bl = second ? blB : blA;
    const float* Wr = second ? WrB : WrA;
    const float* br = second ? brB : brA;
    float* Yl = second ? YlB : YlA;
    float* Yr = second ? YrB : YrA;

    const int tid  = threadIdx.x;
    const int c    = tid % HC;
    const int g    = tid / HC;
    const int row0 = bid * BR;

#pragma unroll
    for (int idx = tid; idx < BR * F4; idx += 256) {
        int r = idx / F4, q = idx % F4;
        reinterpret_cast<float4*>(&xs[r][0])[q] =
            reinterpret_cast<const float4*>(X + (size_t)(row0 + r) * FI)[q];
    }
    __syncthreads();

    float al0[R], al1[R], ar0[R], ar1[R];
    const float bl0 = bl[c], bl1 = bl[c + HC], br0 = br[c], br1 = br[c + HC];
#pragma unroll
    for (int r = 0; r < R; ++r) { al0[r] = bl0; al1[r] = bl1; ar0[r] = br0; ar1[r] = br1; }

    const int rb = g * R;
#pragma unroll
    for (int i0 = 0; i0 < FI; i0 += 4) {
        float4 xv[R];
#pragma unroll
        for (int r = 0; r < R; ++r)
            xv[r] = *reinterpret_cast<const float4*>(&xs[rb + r][i0]);
#pragma unroll
        for (int j = 0; j < 4; ++j) {
            const float wl0 = Wl[(i0 + j) * FO + c];
            const float wl1 = Wl[(i0 + j) * FO + c + HC];
            const float wr0 = Wr[(i0 + j) * FO + c];
            const float wr1 = Wr[(i0 + j) * FO + c + HC];
#pragma unroll
            for (int r = 0; r < R; ++r) {
                const float xx = (&xv[r].x)[j];
                al0[r] = fmaf(xx, wl0, al0[r]);
                al1[r] = fmaf(xx, wl1, al1[r]);
                ar0[r] = fmaf(xx, wr0, ar0[r]);
                ar1[r] = fmaf(xx, wr1, ar1[r]);
            }
        }
    }
#pragma unroll
    for (int r = 0; r < R; ++r) {
        const size_t ro = (size_t)(row0 + rb + r) * FO;
        reinterpret_cast<float2*>(Yl + ro)[c] = make_float2(al0[r], al1[r]);
        reinterpret_cast<float2*>(Yr + ro)[c] = make_float2(ar0[r], ar1[r]);
    }
}

// ---------------------------------------------------------------------------
// 2b. Single linear to 96 cols (GRU input gates): Y = X@W^T + b.
// ---------------------------------------------------------------------------
__global__ __launch_bounds__(192) void k_lin96(
    const float* __restrict__ X, const float* __restrict__ W,
    const float* __restrict__ b, float* __restrict__ Y)
{
    __shared__ float wT[32 * 97];
    __shared__ float xs[16][32];

    const int tid = threadIdx.y * 96 + threadIdx.x;
    const int row0 = blockIdx.x * 16;

    for (int idx = tid; idx < 3072; idx += 192) {
        int c = idx >> 5, i = idx & 31;
        wT[i * 97 + c] = W[idx];
    }
    for (int idx = tid; idx < 128; idx += 192)
        reinterpret_cast<float4*>(xs)[idx] =
            reinterpret_cast<const float4*>(X + (size_t)row0 * 32)[idx];
    __syncthreads();

    const int c  = threadIdx.x;
    const int rb = threadIdx.y * 8;
    float acc[8];
    const float bc = b[c];
#pragma unroll
    for (int r = 0; r < 8; ++r) acc[r] = bc;

#pragma unroll
    for (int i = 0; i < 32; ++i) {
        const float w = wT[i * 97 + c];
#pragma unroll
        for (int r = 0; r < 8; ++r)
            acc[r] = fmaf(xs[rb + r][i], w, acc[r]);
    }
#pragma unroll
    for (int r = 0; r < 8; ++r)
        Y[(size_t)(row0 + rb + r) * 96 + c] = acc[r];
}

// ---------------------------------------------------------------------------
// 2c. Serial GRU layer: register weights, shfl broadcast, gi prefetch,
//     exp2-based sigmoid/tanh.
// ---------------------------------------------------------------------------
__global__ __launch_bounds__(64) void k_gru1(
    const float* __restrict__ gi, const float* __restrict__ Whh,
    const float* __restrict__ bhh, float* __restrict__ E)
{
    const int d    = threadIdx.x & 31;
    const int node = blockIdx.x * 2 + (threadIdx.x >> 5);

    float wr_[32], wz_[32], wn_[32];
#pragma unroll
    for (int q = 0; q < 8; ++q) {
        *reinterpret_cast<float4*>(&wr_[q * 4]) =
            reinterpret_cast<const float4*>(Whh + (size_t)d * 32)[q];
        *reinterpret_cast<float4*>(&wz_[q * 4]) =
            reinterpret_cast<const float4*>(Whh + (size_t)(32 + d) * 32)[q];
        *reinterpret_cast<float4*>(&wn_[q * 4]) =
            reinterpret_cast<const float4*>(Whh + (size_t)(64 + d) * 32)[q];
    }
    const float br_ = bhh[d], bz_ = bhh[32 + d], bn_ = bhh[64 + d];

    size_t base = (size_t)node * 96 + d;
    float gr = gi[base], gz = gi[base + 32], gn = gi[base + 64];

    float h = 0.0f;
    for (int t = 0; t < Tt; ++t) {
        float grn = 0.f, gzn = 0.f, gnn = 0.f;
        if (t < Tt - 1) {
            const size_t nb = ((size_t)(t + 1) * Nn + node) * 96 + d;
            grn = gi[nb]; gzn = gi[nb + 32]; gnn = gi[nb + 64];
        }
        float ar = br_, az = bz_, an = bn_;
#pragma unroll
        for (int i = 0; i < 32; ++i) {
            const float hv = __shfl(h, i, 32);
            ar = fmaf(wr_[i], hv, ar);
            az = fmaf(wz_[i], hv, az);
            an = fmaf(wn_[i], hv, an);
        }
        const float r = __builtin_amdgcn_rcpf(1.0f + __builtin_amdgcn_exp2f(-LOG2E * (gr + ar)));
        const float z = __builtin_amdgcn_rcpf(1.0f + __builtin_amdgcn_exp2f(-LOG2E * (gz + az)));
        const float nn2 = fast_tanh(gn + r * an);
        h = (1.0f - z) * nn2 + z * h;
        E[((size_t)t * Nn + node) * 32 + d] = h;
        gr = grn; gz = gzn; gn = gnn;
    }
}

// ---------------------------------------------------------------------------
// Shared GATv2 C=64 PAIR body: TWO targets per wave (one per 32-lane half).
// No-max softmax, v_exp, ds_bpermute alpha broadcast.
// ---------------------------------------------------------------------------
__device__ __forceinline__ void gat64_pair_body(
    const float* __restrict__ gl, const float* __restrict__ gr,
    const int* __restrict__ srcs, const float* __restrict__ att,
    const float* __restrict__ bias, int wv, int lane,
    float* __restrict__ out)
{
    const int tgt = 2 * wv + (lane >> 5);
    const int t = tgt >> 10;
    const int n = tgt & (Nn - 1);
    const int c = lane & 31;

    const float2* grrow = reinterpret_cast<const float2*>(gr) + (size_t)tgt * 64;
    const float2 grl0 = grrow[c];
    const float2 grl1 = grrow[32 + c];
    const float a00 = att[c],      a01 = att[32 + c];
    const float a10 = att[64 + c], a11 = att[96 + c];

    const int4* sp = reinterpret_cast<const int4*>(srcs + ((size_t)t * Nn + n) * KN);
    const int4 sA = sp[0], sB = sp[1], sC = sp[2], sD = sp[3];
    int s[KN] = {sA.x, sA.y, sA.z, sA.w, sB.x, sB.y, sB.z, sB.w,
                 sC.x, sC.y, sC.z, sC.w, sD.x, sD.y, sD.z, sD.w};

    const float2* glt = reinterpret_cast<const float2*>(gl) + ((size_t)t * Nn * 64);

    float2 g0[KN], g1[KN];
    float p0[KN], p1[KN];
#pragma unroll
    for (int k = 0; k < KN; ++k) {
        const unsigned ro = (unsigned)(s[k] << 6);
        g0[k] = glt[ro | c];
        g1[k] = glt[ro | (32 + c)];
        float e00 = g0[k].x + grl0.x; e00 = fmaxf(e00, 0.2f * e00);
        float e01 = g1[k].x + grl1.x; e01 = fmaxf(e01, 0.2f * e01);
        float e10 = g0[k].y + grl0.y; e10 = fmaxf(e10, 0.2f * e10);
        float e11 = g1[k].y + grl1.y; e11 = fmaxf(e11, 0.2f * e11);
        p0[k] = fmaf(e01, a01, e00 * a00);
        p1[k] = fmaf(e11, a11, e10 * a10);
    }
    float lo0 = fold16(p0, lane); lo0 += lane_xor<16>(lo0);
    float lo1 = fold16(p1, lane); lo1 += lane_xor<16>(lo1);

    const float e0 = __builtin_amdgcn_exp2f(LOG2E * lo0);
    const float e1 = __builtin_amdgcn_exp2f(LOG2E * lo1);
    const float A0 = e0 * __builtin_amdgcn_rcpf(rsum16(e0));
    const float A1 = e1 * __builtin_amdgcn_rcpf(rsum16(e1));

    const int pbase = (lane & 32) << 2;
    float acc00 = 0.0f, acc01 = 0.0f, acc10 = 0.0f, acc11 = 0.0f;
#pragma unroll
    for (int k = 0; k < KN; ++k) {
        const float b0 = bperm_alpha(A0, pbase, rev4(k));
        const float b1 = bperm_alpha(A1, pbase, rev4(k));
        acc00 = fmaf(b0, g0[k].x, acc00);
        acc01 = fmaf(b0, g1[k].x, acc01);
        acc10 = fmaf(b1, g0[k].y, acc10);
        acc11 = fmaf(b1, g1[k].y, acc11);
    }
    float r0 = 0.5f * (acc00 + acc10) + bias[c];
    float r1 = 0.5f * (acc01 + acc11) + bias[32 + c];
    out[(size_t)tgt * 64 + c]      = elu(r0);
    out[(size_t)tgt * 64 + 32 + c] = elu(r1);
}

// ---------------------------------------------------------------------------
// 3. GATv2 C=64 pair kernel (g1).
// ---------------------------------------------------------------------------
__global__ __launch_bounds__(256, 4) void k_gat64p(
    const float* __restrict__ gl, const float* __restrict__ gr,
    const int* __restrict__ srcs, const float* __restrict__ att,
    const float* __restrict__ bias, float* __restrict__ out, int pairs)
{
    const int lane = threadIdx.x & 63;
    const int w = threadIdx.x >> 6;
    const int gridB = pairs >> 2;
    const int chunk = gridB >> 3;
    const int bid = blockIdx.x;
    const int lb = (bid & 7) * chunk + (bid >> 3);
    const int wv = lb * 4 + w;
    gat64_pair_body(gl, gr, srcs, att, bias, wv, lane, out);
}

// ---------------------------------------------------------------------------
// 3d. Dual-path GATv2 C=64 pair kernel (r1 + f1 tails in one launch).
// ---------------------------------------------------------------------------
__global__ __launch_bounds__(256, 4) void k_gat64p2(
    const float* __restrict__ glA, const float* __restrict__ grA,
    const int* __restrict__ srcsA, const float* __restrict__ attA,
    const float* __restrict__ biasA, float* __restrict__ outA,
    const float* __restrict__ glB, const float* __restrict__ grB,
    const int* __restrict__ srcsB, const float* __restrict__ attB,
    const float* __restrict__ biasB, float* __restrict__ outB)
{
    constexpr int pairs = (Tt - 1) * Nn / 2;   // 15872
    constexpr int gridH = pairs >> 2;           // 3968
    constexpr int chunk = gridH >> 3;           // 496

    int bid = blockIdx.x;
    const bool second = bid >= gridH;
    if (second) bid -= gridH;

    const float* gl   = second ? glB   : glA;
    const float* gr   = second ? grB   : grA;
    const int*   srcs = second ? srcsB : srcsA;
    const float* att  = second ? attB  : attA;
    const float* bias = second ? biasB : biasA;
    float*       out  = second ? outB  : outA;

    const int lane = threadIdx.x & 63;
    const int w = threadIdx.x >> 6;
    const int lb = (bid & 7) * chunk + (bid >> 3);
    const int wv = lb * 4 + w;
    gat64_pair_body(gl, gr, srcs, att, bias, wv, lane, out);
}

// ---------------------------------------------------------------------------
// 3b. GATv2 C=32: two targets per wave, same softmax/bpermute scheme.
// ---------------------------------------------------------------------------
__global__ __launch_bounds__(256, 4) void k_gat32(
    const float* __restrict__ gl, const float* __restrict__ gr,
    const int* __restrict__ srcs, const float* __restrict__ att,
    const float* __restrict__ bias, float* __restrict__ out, int waves)
{
    const int lane = threadIdx.x & 63;
    const int w = threadIdx.x >> 6;
    const int gridB = waves >> 2;
    const int chunk = gridB >> 3;
    const int bid = blockIdx.x;
    const int lb = (bid & 7) * chunk + (bid >> 3);
    const int wv = lb * 4 + w;
    const int tgt = 2 * wv + (lane >> 5);
    const int t = tgt >> 10;
    const int n = tgt & (Nn - 1);
    const int c = lane & 31;

    const float2 grl = reinterpret_cast<const float2*>(gr + (size_t)tgt * 64)[c];
    const float a0 = att[c], a1 = att[32 + c];

    const int4* sp = reinterpret_cast<const int4*>(srcs + ((size_t)t * Nn + n) * KN);
    const int4 sA = sp[0], sB = sp[1], sC = sp[2], sD = sp[3];
    int s[KN] = {sA.x, sA.y, sA.z, sA.w, sB.x, sB.y, sB.z, sB.w,
                 sC.x, sC.y, sC.z, sC.w, sD.x, sD.y, sD.z, sD.w};

    const float2* glt = reinterpret_cast<const float2*>(gl) + ((size_t)t * Nn * 32);

    float2 g[KN];
    float p0[KN], p1[KN];
#pragma unroll
    for (int k = 0; k < KN; ++k) {
        g[k] = glt[(unsigned)((s[k] << 5) | c)];
        float e0 = g[k].x + grl.x; e0 = fmaxf(e0, 0.2f * e0);
        float e1 = g[k].y + grl.y; e1 = fmaxf(e1, 0.2f * e1);
        p0[k] = e0 * a0; p1[k] = e1 * a1;
    }
    float lo0 = fold16(p0, lane); lo0 += lane_xor<16>(lo0);
    float lo1 = fold16(p1, lane); lo1 += lane_xor<16>(lo1);

    const float e0 = __builtin_amdgcn_exp2f(LOG2E * lo0);
    const float e1 = __builtin_amdgcn_exp2f(LOG2E * lo1);
    const float A0 = e0 * __builtin_amdgcn_rcpf(rsum16(e0));
    const float A1 = e1 * __builtin_amdgcn_rcpf(rsum16(e1));

    const int pbase = (lane & 32) << 2;
    float acc0 = 0.0f, acc1 = 0.0f;
#pragma unroll
    for (int k = 0; k < KN; ++k) {
        const float b0 = bperm_alpha(A0, pbase, rev4(k));
        const float b1 = bperm_alpha(A1, pbase, rev4(k));
        acc0 = fmaf(b0, g[k].x, acc0);
        acc1 = fmaf(b1, g[k].y, acc1);
    }
    float res = 0.5f * (acc0 + acc1) + bias[c];
    out[(size_t)tgt * 32 + c] = elu(res);
}

// ---------------------------------------------------------------------------
// 4. Dual register-blocked MLP head: out = tanh(in@W2+b2)@W3+b3.
// ---------------------------------------------------------------------------
__global__ __launch_bounds__(256) void k_head2(
    const float* __restrict__ inA, const float* __restrict__ W3A,
    const float* __restrict__ b3A, float* __restrict__ outA,
    const float* __restrict__ inB, const float* __restrict__ W3B,
    const float* __restrict__ b3B, float* __restrict__ outB,
    const float* __restrict__ W2, const float* __restrict__ b2)
{
    __shared__ float xs[32][64];
    __shared__ float tmp[32][64];

    int bid = blockIdx.x;
    const bool second = bid >= 992;
    if (second) bid -= 992;

    const float* in  = second ? inB  : inA;
    const float* W3  = second ? W3B  : W3A;
    const float* b3  = second ? b3B  : b3A;
    float*       out = second ? outB : outA;

    const int c = threadIdx.x;
    const int g = threadIdx.y;
    const int tid = g * 64 + c;
    const int row0 = bid * 32;

    for (int idx = tid; idx < 32 * 16; idx += 256) {
        int r = idx >> 4, q = idx & 15;
        reinterpret_cast<float4*>(&xs[r][0])[q] =
            reinterpret_cast<const float4*>(in + (size_t)(row0 + r) * 64)[q];
    }
    __syncthreads();

    const int rb = g * 8;
    float acc[8];
    const float bc = b2[c];
#pragma unroll
    for (int r = 0; r < 8; ++r) acc[r] = bc;
#pragma unroll
    for (int i = 0; i < 64; ++i) {
        const float w2 = W2[i * 64 + c];
#pragma unroll
        for (int r = 0; r < 8; ++r)
            acc[r] = fmaf(xs[rb + r][i], w2, acc[r]);
    }
#pragma unroll
    for (int r = 0; r < 8; ++r) tmp[rb + r][c] = fast_tanh(acc[r]);

    const int cc = c < 50 ? c : 0;
    float a[8];
    const float b3c = b3[cc];
#pragma unroll
    for (int r = 0; r < 8; ++r) a[r] = b3c;
#pragma unroll
    for (int j = 0; j < 64; ++j) {
        const float w3 = W3[j * 50 + cc];
#pragma unroll
        for (int r = 0; r < 8; ++r)
            a[r] = fmaf(tmp[rb + r][j], w3, a[r]);
    }
    if (c < 50) {
#pragma unroll
        for (int r = 0; r < 8; ++r)
            out[(size_t)(row0 + rb + r) * 50 + c] = a[r];
    }
}

// ---------------------------------------------------------------------------
extern "C" void kernel_launch(void* const* d_in, const int* in_sizes, int n_in,
                              void* d_out, int out_size, void* d_ws, size_t ws_size,
                              hipStream_t stream)
{
    const float* x    = (const float*)d_in[0];
    const int*   edge = (const int*)d_in[1];

    const float *g1_Wl = (const float*)d_in[2],  *g1_bl = (const float*)d_in[3];
    const float *g1_Wr = (const float*)d_in[4],  *g1_br = (const float*)d_in[5];
    const float *g1_att= (const float*)d_in[6],  *g1_b  = (const float*)d_in[7];
    const float *g2_Wl = (const float*)d_in[8],  *g2_bl = (const float*)d_in[9];
    const float *g2_Wr = (const float*)d_in[10], *g2_br = (const float*)d_in[11];
    const float *g2_att= (const float*)d_in[12], *g2_b  = (const float*)d_in[13];
    const float *r1_Wl = (const float*)d_in[14], *r1_bl = (const float*)d_in[15];
    const float *r1_Wr = (const float*)d_in[16], *r1_br = (const float*)d_in[17];
    const float *r1_att= (const float*)d_in[18], *r1_b  = (const float*)d_in[19];
    const float *f1_Wl = (const float*)d_in[20], *f1_bl = (const float*)d_in[21];
    const float *f1_Wr = (const float*)d_in[22], *f1_br = (const float*)d_in[23];
    const float *f1_att= (const float*)d_in[24], *f1_b  = (const float*)d_in[25];
    const float *gru0_Wih = (const float*)d_in[26], *gru0_Whh = (const float*)d_in[27];
    const float *gru0_bih = (const float*)d_in[28], *gru0_bhh = (const float*)d_in[29];
    const float *gru1_Wih = (const float*)d_in[30], *gru1_Whh = (const float*)d_in[31];
    const float *gru1_bih = (const float*)d_in[32], *gru1_bhh = (const float*)d_in[33];
    const float *rec2_W = (const float*)d_in[34], *rec2_b = (const float*)d_in[35];
    const float *rec3_W = (const float*)d_in[36], *rec3_b = (const float*)d_in[37];
    const float *fore3_W= (const float*)d_in[38], *fore3_b= (const float*)d_in[39];

    // workspace layout
    char* ws = (char*)d_ws;
    int*   srcs = (int*)ws;                              // [32][1024][16] (2 MB)
    float* buf1 = (float*)(ws + (4u << 20));             // [32768,128]
    float* buf2 = buf1 + (size_t)32768 * 128;
    float* buf3 = buf2 + (size_t)32768 * 128;
    float* buf4 = buf3 + (size_t)32768 * 128;
    float* buf5 = buf4 + (size_t)32768 * 128;            // [32768,64]
    float* buf6 = buf5 + (size_t)32768 * 64;             // [32768,32]

    float* recon = (float*)d_out;                        // [31,1024,50]
    float* fore  = recon + (size_t)31 * 1024 * 50;       // [31,1024,50]
    float* E     = fore  + (size_t)31 * 1024 * 50;       // [32,1024,32]

    // 1. adjacency -> source lists (512 blocks, 2 blocks/CU co-resident)
    k_srcs<<<Tt * 16, 1024, 0, stream>>>(edge, srcs);

    // 2. GAT g1 (64 -> 64): pair kernel, 16384 pairs
    k_lin2t<64, 128><<<1024, 256, 0, stream>>>(x, g1_Wl, g1_bl, g1_Wr, g1_br, buf1, buf2, 32768);
    k_gat64p<<<4096, 256, 0, stream>>>(buf1, buf2, srcs, g1_att, g1_b, buf5, 16384);

    // 3. GAT g2 (64 -> 32)
    k_lin2t<64, 64><<<512, 256, 0, stream>>>(buf5, g2_Wl, g2_bl, g2_Wr, g2_br, buf1, buf2, 32768);
    k_gat32<<<4096, 256, 0, stream>>>(buf1, buf2, srcs, g2_att, g2_b, buf6, 16384);

    // 4. GRU stack
    k_lin96<<<2048, dim3(96, 2), 0, stream>>>(buf6, gru0_Wih, gru0_bih, buf1);   // GI0
    k_gru1<<<512, 64, 0, stream>>>(buf1, gru0_Whh, gru0_bhh, buf5);              // E0
    k_lin96<<<2048, dim3(96, 2), 0, stream>>>(buf5, gru1_Wih, gru1_bih, buf2);   // GI1
    k_gru1<<<512, 64, 0, stream>>>(buf2, gru1_Whh, gru1_bhh, E);                 // E

    // 5. r1+f1 projections in one launch
    k_lin2td<<<1984, 256, 0, stream>>>(E,
        r1_Wl, r1_bl, r1_Wr, r1_br, buf1, buf2,
        f1_Wl, f1_bl, f1_Wr, f1_br, buf3, buf4);

    // 6. dual GAT bodies (one launch), then register-blocked dual head
    k_gat64p2<<<7936, 256, 0, stream>>>(
        buf1, buf2, srcs + (size_t)KN * Nn, r1_att, r1_b, buf5,
        buf3, buf4, srcs,                   f1_att, f1_b, buf6);
    k_head2<<<1984, dim3(64, 4), 0, stream>>>(
        buf5, rec3_W, rec3_b, recon,
        buf6, fore3_W, fore3_b, fore,
        rec2_W, rec2_b);

    (void)in_sizes; (void)n_in; (void)out_size; (void)ws_size;
}